// Round 1
// baseline (746.156 us; speedup 1.0000x reference)
//
#include <hip/hip_runtime.h>
#include <math.h>

#define T_LEN 8192
#define LOG2T 13
#define NSLICE 16

// ---------------------------------------------------------------------------
// Kernel 1: per-signal FFT-based Hilbert -> unit phasors Z
// DIF forward (natural->bitrev), filter in bitrev order, DIT inverse
// (bitrev->natural). 1/N scale skipped (cancels in normalization).
// ---------------------------------------------------------------------------
__global__ __launch_bounds__(256) void fft_hilbert_kernel(
    const float* __restrict__ x, float2* __restrict__ z)
{
    __shared__ float re[T_LEN];
    __shared__ float im[T_LEN];
    const int sig = blockIdx.x;            // b*64 + c
    const int tid = threadIdx.x;
    const float* xp = x + (size_t)sig * T_LEN;

    for (int t = tid; t < T_LEN; t += 256) { re[t] = xp[t]; im[t] = 0.f; }
    __syncthreads();

    // forward DIF, twiddle exp(-2*pi*i*jj/m)
    for (int s = 0; s < LOG2T; ++s) {
        const int lh = LOG2T - 1 - s;      // log2(half)
        const int half = 1 << lh;
        const float ang_scale = -6.283185307179586f / (float)(half << 1);
        for (int u = tid; u < (T_LEN / 2); u += 256) {
            int blk = u >> lh;
            int jj  = u & (half - 1);
            int i1  = (blk << (lh + 1)) + jj;
            int i2  = i1 + half;
            float ar = re[i1], ai = im[i1];
            float br = re[i2], bi = im[i2];
            re[i1] = ar + br; im[i1] = ai + bi;
            float tr = ar - br, ti = ai - bi;
            float c, sn;
            __sincosf(ang_scale * (float)jj, &sn, &c);
            re[i2] = tr * c - ti * sn;
            im[i2] = tr * sn + ti * c;
        }
        __syncthreads();
    }

    // Hilbert filter: spectrum at position p is bin k = bitrev13(p)
    for (int p = tid; p < T_LEN; p += 256) {
        int k = (int)(__brev((unsigned)p) >> (32 - LOG2T));
        float f = (k == 0 || k == (T_LEN / 2)) ? 1.f
                  : (k < (T_LEN / 2) ? 2.f : 0.f);
        re[p] *= f; im[p] *= f;
    }
    __syncthreads();

    // inverse DIT, twiddle exp(+2*pi*i*jj/m), bitrev input -> natural output
    for (int s = 0; s < LOG2T; ++s) {
        const int half = 1 << s;
        const float ang_scale = 6.283185307179586f / (float)(half << 1);
        for (int u = tid; u < (T_LEN / 2); u += 256) {
            int blk = u >> s;
            int jj  = u & (half - 1);
            int i1  = (blk << (s + 1)) + jj;
            int i2  = i1 + half;
            float c, sn;
            __sincosf(ang_scale * (float)jj, &sn, &c);
            float br = re[i2] * c - im[i2] * sn;
            float bi = re[i2] * sn + im[i2] * c;
            float ar = re[i1], ai = im[i1];
            re[i1] = ar + br; im[i1] = ai + bi;
            re[i2] = ar - br; im[i2] = ai - bi;
        }
        __syncthreads();
    }

    // normalize to unit phasors
    float2* zp = z + (size_t)sig * T_LEN;
    for (int t = tid; t < T_LEN; t += 256) {
        float ar = re[t], ai = im[t];
        float inv = rsqrtf(ar * ar + ai * ai);
        float2 v; v.x = ar * inv; v.y = ai * inv;
        zp[t] = v;
    }
}

// ---------------------------------------------------------------------------
// Kernel 2: partial complex Gram G[b] += Z[b] * conj(Z[b])^T over a T-slice.
// grid (32, NSLICE), 256 thr; each thread owns a 4x4 (i,j) tile with
// i in {q,q+16,q+32,q+48} (q=tid>>4), j in {p,p+16,p+32,p+48} (p=tid&15)
// -> conflict-free LDS reads with zs[64][65] padding.
// ---------------------------------------------------------------------------
__global__ __launch_bounds__(256) void gram_kernel(
    const float2* __restrict__ z, float* __restrict__ part)
{
    const int b   = blockIdx.x;
    const int sl  = blockIdx.y;
    const int tid = threadIdx.x;
    const int q = tid >> 4;   // 0..15
    const int p = tid & 15;   // 0..15
    __shared__ float2 zs[64][65];

    float accr[4][4];
    float acci[4][4];
    #pragma unroll
    for (int a = 0; a < 4; ++a)
        #pragma unroll
        for (int c = 0; c < 4; ++c) { accr[a][c] = 0.f; acci[a][c] = 0.f; }

    const int t0 = sl * (T_LEN / NSLICE);
    for (int chunk = 0; chunk < (T_LEN / NSLICE) / 64; ++chunk) {
        const int tc = t0 + chunk * 64;
        for (int idx = tid; idx < 64 * 64; idx += 256) {
            int row = idx >> 6, col = idx & 63;
            zs[row][col] = z[((size_t)b * 64 + row) * T_LEN + tc + col];
        }
        __syncthreads();
        for (int tt = 0; tt < 64; ++tt) {
            float2 a[4], bb[4];
            #pragma unroll
            for (int r = 0; r < 4; ++r) a[r]  = zs[q + 16 * r][tt];
            #pragma unroll
            for (int r = 0; r < 4; ++r) bb[r] = zs[p + 16 * r][tt];
            #pragma unroll
            for (int ri = 0; ri < 4; ++ri)
                #pragma unroll
                for (int rj = 0; rj < 4; ++rj) {
                    accr[ri][rj] += a[ri].x * bb[rj].x + a[ri].y * bb[rj].y;
                    acci[ri][rj] += a[ri].y * bb[rj].x - a[ri].x * bb[rj].y;
                }
        }
        __syncthreads();
    }

    float* pp = part + (size_t)(b * NSLICE + sl) * 4096 * 2;
    #pragma unroll
    for (int ri = 0; ri < 4; ++ri)
        #pragma unroll
        for (int rj = 0; rj < 4; ++rj) {
            int i = q + 16 * ri, j = p + 16 * rj;
            int e = i * 64 + j;
            pp[e * 2 + 0] = accr[ri][rj];
            pp[e * 2 + 1] = acci[ri][rj];
        }
}

// ---------------------------------------------------------------------------
// Kernel 3: reduce partials, PLV = |G|/T, zero diagonal -> out0
// ---------------------------------------------------------------------------
__global__ __launch_bounds__(256) void plv_kernel(
    const float* __restrict__ part, float* __restrict__ out0)
{
    const int b = blockIdx.x, tid = threadIdx.x;
    const float2* pf = (const float2*)part;
    for (int e = tid; e < 4096; e += 256) {
        float gr = 0.f, gi = 0.f;
        for (int s = 0; s < NSLICE; ++s) {
            float2 v = pf[(size_t)(b * NSLICE + s) * 4096 + e];
            gr += v.x; gi += v.y;
        }
        int i = e >> 6, j = e & 63;
        float val = (i == j) ? 0.f
                             : sqrtf(gr * gr + gi * gi) * (1.0f / 8192.0f);
        out0[(size_t)b * 4096 + e] = val;
    }
}

// ---------------------------------------------------------------------------
// Kernel 4: GCN (2 layers) + MHA, one workgroup per batch. 64 KB LDS total.
//   C[4096]: conn, later per-head scores
//   A[4096]: M = conn@emb, later P = h1@w2
//   B[8192]: h1 (64x128); later h2 in B[0:4096], qh/kh/vh/oh in B[4096:6144]
// ---------------------------------------------------------------------------
__global__ __launch_bounds__(256) void gnn_mha_kernel(
    const float* __restrict__ conn, const float* __restrict__ emb,
    const float* __restrict__ w1,   const float* __restrict__ b1,
    const float* __restrict__ w2,   const float* __restrict__ b2,
    const float* __restrict__ ipw,  const float* __restrict__ ipb,
    const float* __restrict__ opw,  const float* __restrict__ opb,
    float* __restrict__ out1, float* __restrict__ out2)
{
    __shared__ float C[64 * 64];
    __shared__ float A[64 * 64];
    __shared__ float B[64 * 128];
    const int b = blockIdx.x, tid = threadIdx.x;

    // load conn -> C, emb -> B[0:4096]
    for (int e = tid; e < 4096; e += 256) {
        C[e] = conn[(size_t)b * 4096 + e];
        B[e] = emb[e];
    }
    __syncthreads();
    // M = conn @ emb -> A       (using (conn@emb)@w1 == conn@(emb@w1))
    for (int e = tid; e < 4096; e += 256) {
        int i = e >> 6, f = e & 63;
        float s = 0.f;
        for (int k = 0; k < 64; ++k) s += C[i * 64 + k] * B[k * 64 + f];
        A[e] = s;
    }
    __syncthreads();
    // h1 = relu(M @ w1 + b1) -> B (64x128)
    for (int e = tid; e < 64 * 128; e += 256) {
        int i = e >> 7, f = e & 127;
        float s = b1[f];
        for (int k = 0; k < 64; ++k) s += A[i * 64 + k] * w1[k * 128 + f];
        B[e] = fmaxf(s, 0.f);
    }
    __syncthreads();
    // P = h1 @ w2 -> A (64x64)
    for (int e = tid; e < 4096; e += 256) {
        int i = e >> 6, f = e & 63;
        float s = 0.f;
        for (int k = 0; k < 128; ++k) s += B[i * 128 + k] * w2[k * 64 + f];
        A[e] = s;
    }
    __syncthreads();
    // h2 = conn @ P + b2 -> B[0:4096], also write out2
    for (int e = tid; e < 4096; e += 256) {
        int i = e >> 6, f = e & 63;
        float s = b2[f];
        for (int k = 0; k < 64; ++k) s += C[i * 64 + k] * A[k * 64 + f];
        B[e] = s;
        out2[(size_t)b * 4096 + e] = s;
    }
    __syncthreads();

    // ---- MHA (8 heads, D=8); h2 lives in B[0:4096] ----
    float gacc[16];
    #pragma unroll
    for (int r = 0; r < 16; ++r) gacc[r] = 0.f;
    const int gn  = tid >> 2;            // output row n (4 threads per row)
    const int ge0 = (tid & 3) * 16;      // output col base
    float* qh = B + 4096;
    float* kh = B + 4096 + 512;
    float* vh = B + 4096 + 1024;
    float* oh = B + 4096 + 1536;
    const float iscale = 0.35355339059327373f;  // 1/sqrt(8)

    for (int h = 0; h < 8; ++h) {
        // qh/kh/vh (64x8 each) from h2 and in_proj rows {h8+d, 64+h8+d, 128+h8+d}
        for (int e = tid; e < 512; e += 256) {
            int n = e >> 3, d = e & 7;
            float sq = ipb[h * 8 + d];
            float sk = ipb[64 + h * 8 + d];
            float sv = ipb[128 + h * 8 + d];
            for (int k = 0; k < 64; ++k) {
                float hv = B[n * 64 + k];
                sq += hv * ipw[(h * 8 + d) * 64 + k];
                sk += hv * ipw[(64 + h * 8 + d) * 64 + k];
                sv += hv * ipw[(128 + h * 8 + d) * 64 + k];
            }
            qh[e] = sq; kh[e] = sk; vh[e] = sv;
        }
        __syncthreads();
        // scores -> C
        for (int e = tid; e < 4096; e += 256) {
            int n = e >> 6, m = e & 63;
            float s = 0.f;
            #pragma unroll
            for (int d = 0; d < 8; ++d) s += qh[n * 8 + d] * kh[m * 8 + d];
            C[e] = s * iscale;
        }
        __syncthreads();
        // row softmax (threads 0..63)
        if (tid < 64) {
            float mx = -1e30f;
            for (int m = 0; m < 64; ++m) mx = fmaxf(mx, C[tid * 64 + m]);
            float sum = 0.f;
            for (int m = 0; m < 64; ++m) {
                float ev = __expf(C[tid * 64 + m] - mx);
                C[tid * 64 + m] = ev; sum += ev;
            }
            float inv = 1.f / sum;
            for (int m = 0; m < 64; ++m) C[tid * 64 + m] *= inv;
        }
        __syncthreads();
        // oh = attn @ vh (64x8)
        for (int e = tid; e < 512; e += 256) {
            int n = e >> 3, d = e & 7;
            float s = 0.f;
            for (int m = 0; m < 64; ++m) s += C[n * 64 + m] * vh[m * 8 + d];
            oh[e] = s;
        }
        __syncthreads();
        // graph[n][e] += sum_d oh[n][d] * opw[e][h*8+d]  (accumulate in regs)
        #pragma unroll
        for (int r = 0; r < 16; ++r) {
            float s = gacc[r];
            #pragma unroll
            for (int d = 0; d < 8; ++d)
                s += oh[gn * 8 + d] * opw[(ge0 + r) * 64 + h * 8 + d];
            gacc[r] = s;
        }
        __syncthreads();
    }
    #pragma unroll
    for (int r = 0; r < 16; ++r) {
        int e = ge0 + r;
        out1[(size_t)b * 4096 + gn * 64 + e] = gacc[r] + opb[e];
    }
}

// ---------------------------------------------------------------------------
extern "C" void kernel_launch(void* const* d_in, const int* in_sizes, int n_in,
                              void* d_out, int out_size, void* d_ws, size_t ws_size,
                              hipStream_t stream)
{
    const float* x   = (const float*)d_in[0];
    const float* emb = (const float*)d_in[1];
    const float* w1  = (const float*)d_in[2];
    const float* b1  = (const float*)d_in[3];
    const float* w2  = (const float*)d_in[4];
    const float* b2  = (const float*)d_in[5];
    const float* ipw = (const float*)d_in[6];
    const float* ipb = (const float*)d_in[7];
    const float* opw = (const float*)d_in[8];
    const float* opb = (const float*)d_in[9];

    float* out  = (float*)d_out;
    float* out0 = out;               // connectivity: 32*64*64
    float* out1 = out + 131072;      // graph_features
    float* out2 = out + 262144;      // h2

    float2* z   = (float2*)d_ws;                                   // 134.2 MB
    float* part = (float*)((char*)d_ws + (size_t)32 * 64 * 8192 * 8); // 16.8 MB

    hipLaunchKernelGGL(fft_hilbert_kernel, dim3(32 * 64), dim3(256), 0, stream,
                       x, z);
    hipLaunchKernelGGL(gram_kernel, dim3(32, NSLICE), dim3(256), 0, stream,
                       z, part);
    hipLaunchKernelGGL(plv_kernel, dim3(32), dim3(256), 0, stream, part, out0);
    hipLaunchKernelGGL(gnn_mha_kernel, dim3(32), dim3(256), 0, stream,
                       out0, emb, w1, b1, w2, b2, ipw, ipb, opw, opb,
                       out1, out2);
}

// Round 2
// 611.039 us; speedup vs baseline: 1.2211x; 1.2211x over previous
//
#include <hip/hip_runtime.h>
#include <math.h>

#define T_LEN 8192
#define NSLICE 16

typedef float vf2 __attribute__((ext_vector_type(2)));

// packed fp32 fma: acc.lo += u.lo*v.lo; acc.hi += u.hi*v.hi
#define PK_FMA(acc, u, v) \
    asm("v_pk_fma_f32 %0, %1, %2, %0" : "+v"(acc) : "v"(u), "v"(v))

__device__ __forceinline__ constexpr int br5(int r) {
    return ((r & 1) << 4) | ((r & 2) << 2) | (r & 4) | ((r & 8) >> 2) | ((r & 16) >> 4);
}

// in-register 32-point DIF FFT; output slot r holds bin br5(r); twiddles constant-folded
__device__ __forceinline__ void fft32(float* vr, float* vi)
{
    constexpr float TR[16] = {
        1.0f, 0.9807852804f, 0.9238795325f, 0.8314696123f,
        0.7071067812f, 0.5555702330f, 0.3826834324f, 0.1950903220f,
        0.0f, -0.1950903220f, -0.3826834324f, -0.5555702330f,
        -0.7071067812f, -0.8314696123f, -0.9238795325f, -0.9807852804f };
    constexpr float TI[16] = {
        0.0f, -0.1950903220f, -0.3826834324f, -0.5555702330f,
        -0.7071067812f, -0.8314696123f, -0.9238795325f, -0.9807852804f,
        -1.0f, -0.9807852804f, -0.9238795325f, -0.8314696123f,
        -0.7071067812f, -0.5555702330f, -0.3826834324f, -0.1950903220f };
    #pragma unroll
    for (int s = 0; s < 5; ++s) {
        const int half = 16 >> s;
        #pragma unroll
        for (int g = 0; g < (1 << s); ++g) {
            #pragma unroll
            for (int jj = 0; jj < half; ++jj) {
                const int i1 = g * (half << 1) + jj;
                const int i2 = i1 + half;
                const int q = jj << s;
                float ar = vr[i1], ai = vi[i1];
                float br = vr[i2], bi = vi[i2];
                vr[i1] = ar + br; vi[i1] = ai + bi;
                float dr = ar - br, di = ai - bi;
                vr[i2] = dr * TR[q] - di * TI[q];
                vi[i2] = dr * TI[q] + di * TR[q];
            }
        }
    }
}

// Full 8192-point forward FFT (4-step: FFT32(regs) -> twiddle -> LDS transpose
// -> FFT32(regs) -> twiddle -> cross-lane FFT8). Input: vr/vi[n1] = f[n1*256+t].
// Output: slot r of thread t holds bin k = (t>>3) + 32*br5(r) + 1024*br3(t&7).
__device__ __forceinline__ void big_fft(float* vr, float* vi, float2* lds,
                                        int t, int j, int row)
{
    fft32(vr, vi);
    const float base1 = -7.669903939428206e-4f * (float)t;   // -2pi/8192 * t
    #pragma unroll
    for (int r = 0; r < 32; ++r) {
        const int k1 = br5(r);
        if (k1) {
            float c, s; __sincosf(base1 * (float)k1, &s, &c);
            float xr = vr[r], xi = vi[r];
            vr[r] = xr * c - xi * s;
            vi[r] = xr * s + xi * c;
        }
    }
    __syncthreads();                                          // lds safe to overwrite
    #pragma unroll
    for (int r = 0; r < 32; ++r) {
        int a = (br5(r) << 8) + t;
        lds[a ^ (((a >> 8) & 7) << 3)] = make_float2(vr[r], vi[r]);
    }
    __syncthreads();
    #pragma unroll
    for (int m1 = 0; m1 < 32; ++m1) {
        int a = (row << 8) + (m1 << 3) + j;
        float2 v = lds[a ^ (((a >> 8) & 7) << 3)];
        vr[m1] = v.x; vi[m1] = v.y;
    }
    fft32(vr, vi);
    const float base2 = -0.02454369260617026f * (float)j;     // -2pi/256 * j
    #pragma unroll
    for (int r = 0; r < 32; ++r) {
        const int k1p = br5(r);
        if (k1p) {
            float c, s; __sincosf(base2 * (float)k1p, &s, &c);
            float xr = vr[r], xi = vi[r];
            vr[r] = xr * c - xi * s;
            vi[r] = xr * s + xi * c;
        }
    }
    // cross-lane FFT_8 over j (DIF; output lane j holds bin br3(j))
    const float R2 = 0.7071067811865475f;
    const int jm = j & 3;
    float w1r = 1.f, w1i = 0.f;
    if (j >= 4) {
        w1r = (jm == 0) ? 1.f : (jm == 1) ? R2 : (jm == 2) ? 0.f : -R2;
        w1i = (jm == 0) ? 0.f : (jm == 1) ? -R2 : (jm == 2) ? -1.f : -R2;
    }
    const float sg1 = (j < 4) ? 1.f : -1.f;
    const float sg2 = (j & 2) ? -1.f : 1.f;
    const bool tw2 = (j & 2) && (j & 1);
    const float w2r = tw2 ? 0.f : 1.f;
    const float w2i = tw2 ? -1.f : 0.f;
    const float sg3 = (j & 1) ? -1.f : 1.f;
    #pragma unroll
    for (int r = 0; r < 32; ++r) {
        float orr = __shfl_xor(vr[r], 4);
        float oii = __shfl_xor(vi[r], 4);
        float sr = fmaf(sg1, vr[r], orr);
        float si = fmaf(sg1, vi[r], oii);
        float tr = sr * w1r - si * w1i;
        float ti = sr * w1i + si * w1r;
        orr = __shfl_xor(tr, 2);
        oii = __shfl_xor(ti, 2);
        sr = fmaf(sg2, tr, orr);
        si = fmaf(sg2, ti, oii);
        tr = sr * w2r - si * w2i;
        ti = sr * w2i + si * w2r;
        orr = __shfl_xor(tr, 1);
        oii = __shfl_xor(ti, 1);
        vr[r] = fmaf(sg3, tr, orr);
        vi[r] = fmaf(sg3, ti, oii);
    }
}

// ---------------------------------------------------------------------------
// Kernel 1: Hilbert via register-resident FFT. Z stored in a fixed per-signal
// time-permutation (identical across signals; PLV is t-order invariant).
// ---------------------------------------------------------------------------
__global__ __launch_bounds__(256) void fft_hilbert_kernel(
    const float* __restrict__ x, float2* __restrict__ z)
{
    __shared__ float2 lds[8192];   // 64 KB
    const int sig = blockIdx.x;
    const int t = threadIdx.x;
    const int j = t & 7, row = t >> 3;
    const int br3j = ((j & 1) << 2) | (j & 2) | ((j & 4) >> 2);

    float vr[32], vi[32];
    const float* xp = x + (size_t)sig * T_LEN;
    #pragma unroll
    for (int n1 = 0; n1 < 32; ++n1) { vr[n1] = xp[(n1 << 8) + t]; vi[n1] = 0.f; }

    big_fft(vr, vi, lds, t, j, row);

    // conj + Hilbert filter (analytic = conj(F(conj(S*h))), 1/N dropped)
    #pragma unroll
    for (int r = 0; r < 32; ++r) {
        const int k = row + (br5(r) << 5) + (br3j << 10);
        const float h = (k == 0 || k == 4096) ? 1.f : (k < 4096 ? 2.f : 0.f);
        vr[r] = vr[r] * h;
        vi[r] = -vi[r] * h;
    }

    // redistribute to natural order for second transform
    __syncthreads();
    #pragma unroll
    for (int r = 0; r < 32; ++r) {
        int a = row + (br5(r) << 5) + (br3j << 10);
        lds[a ^ (((a >> 10) & 7) << 3)] = make_float2(vr[r], vi[r]);
    }
    __syncthreads();
    #pragma unroll
    for (int n1 = 0; n1 < 32; ++n1) {
        int a = (n1 << 8) + t;
        float2 v = lds[a ^ (((a >> 10) & 7) << 3)];
        vr[n1] = v.x; vi[n1] = v.y;
    }

    big_fft(vr, vi, lds, t, j, row);

    // conj + normalize to unit phasors; coalesced permuted store
    float2* zp = z + (size_t)sig * T_LEN;
    #pragma unroll
    for (int r = 0; r < 32; ++r) {
        float ar = vr[r], ai = -vi[r];
        float inv = rsqrtf(ar * ar + ai * ai);
        float2 o; o.x = ar * inv; o.y = ai * inv;
        zp[(r << 8) + t] = o;
    }
}

// ---------------------------------------------------------------------------
// Kernel 2: partial complex Gram with packed fp32 FMA.
// ---------------------------------------------------------------------------
__global__ __launch_bounds__(256) void gram_kernel(
    const float2* __restrict__ z, float* __restrict__ part)
{
    const int b = blockIdx.x, sl = blockIdx.y, tid = threadIdx.x;
    const int q = tid >> 4, p = tid & 15;
    __shared__ vf2 zs[64][65];

    vf2 accp[4][4], acci[4][4];
    #pragma unroll
    for (int a = 0; a < 4; ++a)
        #pragma unroll
        for (int c = 0; c < 4; ++c) { accp[a][c] = 0.f; acci[a][c] = 0.f; }

    const int t0 = sl * (T_LEN / NSLICE);
    for (int chunk = 0; chunk < (T_LEN / NSLICE) / 64; ++chunk) {
        const int tc = t0 + chunk * 64;
        for (int idx = tid; idx < 64 * 64; idx += 256) {
            int rw = idx >> 6, cl = idx & 63;
            float2 v = z[((size_t)b * 64 + rw) * T_LEN + tc + cl];
            vf2 w; w.x = v.x; w.y = v.y;
            zs[rw][cl] = w;
        }
        __syncthreads();
        for (int tt = 0; tt < 64; ++tt) {
            vf2 a2[4], b2[4], bs[4];
            #pragma unroll
            for (int r = 0; r < 4; ++r) a2[r] = zs[q + 16 * r][tt];
            #pragma unroll
            for (int r = 0; r < 4; ++r) { b2[r] = zs[p + 16 * r][tt]; bs[r] = b2[r].yx; }
            #pragma unroll
            for (int ri = 0; ri < 4; ++ri)
                #pragma unroll
                for (int rj = 0; rj < 4; ++rj) {
                    PK_FMA(accp[ri][rj], a2[ri], b2[rj]);  // {ax*bx, ay*by}
                    PK_FMA(acci[ri][rj], a2[ri], bs[rj]);  // {ax*by, ay*bx}
                }
        }
        __syncthreads();
    }

    float* pp = part + (size_t)(b * NSLICE + sl) * 4096 * 2;
    #pragma unroll
    for (int ri = 0; ri < 4; ++ri)
        #pragma unroll
        for (int rj = 0; rj < 4; ++rj) {
            int i = q + 16 * ri, jj = p + 16 * rj;
            int e = i * 64 + jj;
            pp[e * 2 + 0] = accp[ri][rj].x + accp[ri][rj].y;
            pp[e * 2 + 1] = acci[ri][rj].y - acci[ri][rj].x;  // ay*bx - ax*by
        }
}

// ---------------------------------------------------------------------------
// Kernel 3: reduce partials, PLV = |G|/T, zero diagonal
// ---------------------------------------------------------------------------
__global__ __launch_bounds__(256) void plv_kernel(
    const float* __restrict__ part, float* __restrict__ out0)
{
    const int b = blockIdx.x, tid = threadIdx.x;
    const float2* pf = (const float2*)part;
    for (int e0 = tid; e0 < 1024; e0 += 256) {
        int e = blockIdx.y * 1024 + e0;
        float gr = 0.f, gi = 0.f;
        for (int s = 0; s < NSLICE; ++s) {
            float2 v = pf[(size_t)(b * NSLICE + s) * 4096 + e];
            gr += v.x; gi += v.y;
        }
        int i = e >> 6, jj = e & 63;
        float val = (i == jj) ? 0.f
                              : sqrtf(gr * gr + gi * gi) * (1.0f / 8192.0f);
        out0[(size_t)b * 4096 + e] = val;
    }
}

// ---------------------------------------------------------------------------
// Kernel 4: GCN + MHA. 64 KB arena with phase-overlapped buffers:
//   conn@0(4096,s64)  emb@12288  M@4096  h1@8192(s128)  P@4096
//   h2@8256(s65)  heads: qh@0(s8) kh@512(s9) vh@1088(s9) oh@1664(s9)
//   ipw@2240(24x65)  scores@4096(s65)
// ---------------------------------------------------------------------------
__global__ __launch_bounds__(256) void gnn_mha_kernel(
    const float* __restrict__ conn, const float* __restrict__ emb,
    const float* __restrict__ w1,   const float* __restrict__ b1,
    const float* __restrict__ w2,   const float* __restrict__ b2,
    const float* __restrict__ ipw,  const float* __restrict__ ipb,
    const float* __restrict__ opw,  const float* __restrict__ opb,
    float* __restrict__ out1, float* __restrict__ out2)
{
    __shared__ float S[16384];
    float* conn_s = S;
    float* emb_s  = S + 12288;
    float* M_s    = S + 4096;   // later P
    float* h1_s   = S + 8192;
    float* h2_s   = S + 8256;   // stride 65
    float* qh     = S;          // stride 8
    float* kh     = S + 512;    // stride 9
    float* vh     = S + 1088;   // stride 9
    float* oh     = S + 1664;   // stride 9
    float* ipw_s  = S + 2240;   // 24 x 65
    float* sc     = S + 4096;   // stride 65

    const int b = blockIdx.x, tid = threadIdx.x;
    const int lane = tid & 63, wv = tid >> 6;

    for (int e = tid; e < 4096; e += 256) {
        conn_s[e] = conn[(size_t)b * 4096 + e];
        emb_s[e]  = emb[e];
    }
    __syncthreads();
    // M = conn @ emb
    for (int e = tid; e < 4096; e += 256) {
        int i = e >> 6, f = e & 63;
        float s = 0.f;
        #pragma unroll 8
        for (int k = 0; k < 64; ++k) s += conn_s[i * 64 + k] * emb_s[k * 64 + f];
        M_s[e] = s;
    }
    __syncthreads();
    // h1 = relu(M @ w1 + b1)
    for (int e = tid; e < 8192; e += 256) {
        int i = e >> 7, f = e & 127;
        float s = b1[f];
        #pragma unroll 8
        for (int k = 0; k < 64; ++k) s += M_s[i * 64 + k] * w1[k * 128 + f];
        h1_s[e] = fmaxf(s, 0.f);
    }
    __syncthreads();
    // P = h1 @ w2  (into M_s; M dead)
    for (int e = tid; e < 4096; e += 256) {
        int i = e >> 6, f = e & 63;
        float s = 0.f;
        #pragma unroll 8
        for (int k = 0; k < 128; ++k) s += h1_s[i * 128 + k] * w2[k * 64 + f];
        M_s[e] = s;
    }
    __syncthreads();
    // h2 = conn @ P + b2
    for (int e = tid; e < 4096; e += 256) {
        int i = e >> 6, f = e & 63;
        float s = b2[f];
        #pragma unroll 8
        for (int k = 0; k < 64; ++k) s += conn_s[i * 64 + k] * M_s[k * 64 + f];
        h2_s[i * 65 + f] = s;
        out2[(size_t)b * 4096 + e] = s;
    }
    __syncthreads();

    // ---- MHA ----
    float gacc[16];
    #pragma unroll
    for (int r = 0; r < 16; ++r) gacc[r] = 0.f;
    const int gn  = tid >> 2;
    const int ge0 = (tid & 3) * 16;
    const float iscale = 0.35355339059327373f;

    for (int h = 0; h < 8; ++h) {
        // stage this head's in_proj rows (q:0-7, k:8-15, v:16-23)
        for (int idx = tid; idx < 1536; idx += 256) {
            int rr = idx >> 6, c = idx & 63;
            int grow = (rr < 8) ? (h * 8 + rr)
                     : (rr < 16) ? (64 + h * 8 + rr - 8)
                                 : (128 + h * 8 + rr - 16);
            ipw_s[rr * 65 + c] = ipw[grow * 64 + c];
        }
        __syncthreads();
        // qkv
        for (int e = tid; e < 512; e += 256) {
            int n = e >> 3, d = e & 7;
            float sq = ipb[h * 8 + d];
            float sk = ipb[64 + h * 8 + d];
            float sv = ipb[128 + h * 8 + d];
            #pragma unroll 8
            for (int k = 0; k < 64; ++k) {
                float hv = h2_s[n * 65 + k];
                sq += hv * ipw_s[d * 65 + k];
                sk += hv * ipw_s[(8 + d) * 65 + k];
                sv += hv * ipw_s[(16 + d) * 65 + k];
            }
            qh[n * 8 + d] = sq; kh[n * 9 + d] = sk; vh[n * 9 + d] = sv;
        }
        __syncthreads();
        // fused scores + softmax: each wave owns row n, lane = key index m
        for (int pass = 0; pass < 16; ++pass) {
            int n = pass * 4 + wv;
            float s = 0.f;
            #pragma unroll
            for (int d = 0; d < 8; ++d) s += qh[n * 8 + d] * kh[lane * 9 + d];
            s *= iscale;
            float mx = s;
            #pragma unroll
            for (int off = 1; off < 64; off <<= 1) mx = fmaxf(mx, __shfl_xor(mx, off));
            float ev = __expf(s - mx);
            float sum = ev;
            #pragma unroll
            for (int off = 1; off < 64; off <<= 1) sum += __shfl_xor(sum, off);
            sc[n * 65 + lane] = ev / sum;
        }
        __syncthreads();
        // oh = attn @ v
        for (int e = tid; e < 512; e += 256) {
            int n = e >> 3, d = e & 7;
            float s = 0.f;
            #pragma unroll 8
            for (int m = 0; m < 64; ++m) s += sc[n * 65 + m] * vh[m * 9 + d];
            oh[n * 9 + d] = s;
        }
        __syncthreads();
        // out accumulate: gacc[r] += sum_d oh[gn][d] * opw[ge0+r][h*8+d]
        #pragma unroll
        for (int r = 0; r < 16; ++r) {
            float s = gacc[r];
            #pragma unroll
            for (int d = 0; d < 8; ++d)
                s += oh[gn * 9 + d] * opw[(ge0 + r) * 64 + h * 8 + d];
            gacc[r] = s;
        }
        __syncthreads();
    }
    #pragma unroll
    for (int r = 0; r < 16; ++r) {
        int e = ge0 + r;
        out1[(size_t)b * 4096 + gn * 64 + e] = gacc[r] + opb[e];
    }
}

// ---------------------------------------------------------------------------
extern "C" void kernel_launch(void* const* d_in, const int* in_sizes, int n_in,
                              void* d_out, int out_size, void* d_ws, size_t ws_size,
                              hipStream_t stream)
{
    const float* x   = (const float*)d_in[0];
    const float* emb = (const float*)d_in[1];
    const float* w1  = (const float*)d_in[2];
    const float* b1  = (const float*)d_in[3];
    const float* w2  = (const float*)d_in[4];
    const float* b2  = (const float*)d_in[5];
    const float* ipw = (const float*)d_in[6];
    const float* ipb = (const float*)d_in[7];
    const float* opw = (const float*)d_in[8];
    const float* opb = (const float*)d_in[9];

    float* out  = (float*)d_out;
    float* out0 = out;
    float* out1 = out + 131072;
    float* out2 = out + 262144;

    float2* z   = (float2*)d_ws;
    float* part = (float*)((char*)d_ws + (size_t)32 * 64 * 8192 * 8);

    hipLaunchKernelGGL(fft_hilbert_kernel, dim3(32 * 64), dim3(256), 0, stream,
                       x, z);
    hipLaunchKernelGGL(gram_kernel, dim3(32, NSLICE), dim3(256), 0, stream,
                       z, part);
    hipLaunchKernelGGL(plv_kernel, dim3(32, 4), dim3(256), 0, stream, part, out0);
    hipLaunchKernelGGL(gnn_mha_kernel, dim3(32), dim3(256), 0, stream,
                       out0, emb, w1, b1, w2, b2, ipw, ipb, opw, opb,
                       out1, out2);
}

// Round 3
// 459.469 us; speedup vs baseline: 1.6240x; 1.3299x over previous
//
#include <hip/hip_runtime.h>
#include <math.h>

#define T_LEN 8192
#define NSLICE 16

typedef float vf2 __attribute__((ext_vector_type(2)));

// packed fp32 fma: acc.lo += u.lo*v.lo; acc.hi += u.hi*v.hi
#define PK_FMA(acc, u, v) \
    asm("v_pk_fma_f32 %0, %1, %2, %0" : "+v"(acc) : "v"(u), "v"(v))

__device__ __forceinline__ constexpr int br5(int r) {
    return ((r & 1) << 4) | ((r & 2) << 2) | (r & 4) | ((r & 8) >> 2) | ((r & 16) >> 4);
}

// in-register 32-point DIF FFT; output slot r holds bin br5(r); twiddles constant-folded
__device__ __forceinline__ void fft32(float* vr, float* vi)
{
    constexpr float TR[16] = {
        1.0f, 0.9807852804f, 0.9238795325f, 0.8314696123f,
        0.7071067812f, 0.5555702330f, 0.3826834324f, 0.1950903220f,
        0.0f, -0.1950903220f, -0.3826834324f, -0.5555702330f,
        -0.7071067812f, -0.8314696123f, -0.9238795325f, -0.9807852804f };
    constexpr float TI[16] = {
        0.0f, -0.1950903220f, -0.3826834324f, -0.5555702330f,
        -0.7071067812f, -0.8314696123f, -0.9238795325f, -0.9807852804f,
        -1.0f, -0.9807852804f, -0.9238795325f, -0.8314696123f,
        -0.7071067812f, -0.5555702330f, -0.3826834324f, -0.1950903220f };
    #pragma unroll
    for (int s = 0; s < 5; ++s) {
        const int half = 16 >> s;
        #pragma unroll
        for (int g = 0; g < (1 << s); ++g) {
            #pragma unroll
            for (int jj = 0; jj < half; ++jj) {
                const int i1 = g * (half << 1) + jj;
                const int i2 = i1 + half;
                const int q = jj << s;
                float ar = vr[i1], ai = vi[i1];
                float br = vr[i2], bi = vi[i2];
                vr[i1] = ar + br; vi[i1] = ai + bi;
                float dr = ar - br, di = ai - bi;
                vr[i2] = dr * TR[q] - di * TI[q];
                vi[i2] = dr * TI[q] + di * TR[q];
            }
        }
    }
}

// Full 8192-point forward FFT (4-step). See R1 notes; output bin
// k = (t>>3) + 32*br5(r) + 1024*br3(t&7) in slot r of thread t.
__device__ __forceinline__ void big_fft(float* vr, float* vi, float2* lds,
                                        int t, int j, int row)
{
    fft32(vr, vi);
    const float base1 = -7.669903939428206e-4f * (float)t;   // -2pi/8192 * t
    #pragma unroll
    for (int r = 0; r < 32; ++r) {
        const int k1 = br5(r);
        if (k1) {
            float c, s; __sincosf(base1 * (float)k1, &s, &c);
            float xr = vr[r], xi = vi[r];
            vr[r] = xr * c - xi * s;
            vi[r] = xr * s + xi * c;
        }
    }
    __syncthreads();
    #pragma unroll
    for (int r = 0; r < 32; ++r) {
        int a = (br5(r) << 8) + t;
        lds[a ^ (((a >> 8) & 7) << 3)] = make_float2(vr[r], vi[r]);
    }
    __syncthreads();
    #pragma unroll
    for (int m1 = 0; m1 < 32; ++m1) {
        int a = (row << 8) + (m1 << 3) + j;
        float2 v = lds[a ^ (((a >> 8) & 7) << 3)];
        vr[m1] = v.x; vi[m1] = v.y;
    }
    fft32(vr, vi);
    const float base2 = -0.02454369260617026f * (float)j;     // -2pi/256 * j
    #pragma unroll
    for (int r = 0; r < 32; ++r) {
        const int k1p = br5(r);
        if (k1p) {
            float c, s; __sincosf(base2 * (float)k1p, &s, &c);
            float xr = vr[r], xi = vi[r];
            vr[r] = xr * c - xi * s;
            vi[r] = xr * s + xi * c;
        }
    }
    const float R2 = 0.7071067811865475f;
    const int jm = j & 3;
    float w1r = 1.f, w1i = 0.f;
    if (j >= 4) {
        w1r = (jm == 0) ? 1.f : (jm == 1) ? R2 : (jm == 2) ? 0.f : -R2;
        w1i = (jm == 0) ? 0.f : (jm == 1) ? -R2 : (jm == 2) ? -1.f : -R2;
    }
    const float sg1 = (j < 4) ? 1.f : -1.f;
    const float sg2 = (j & 2) ? -1.f : 1.f;
    const bool tw2 = (j & 2) && (j & 1);
    const float w2r = tw2 ? 0.f : 1.f;
    const float w2i = tw2 ? -1.f : 0.f;
    const float sg3 = (j & 1) ? -1.f : 1.f;
    #pragma unroll
    for (int r = 0; r < 32; ++r) {
        float orr = __shfl_xor(vr[r], 4);
        float oii = __shfl_xor(vi[r], 4);
        float sr = fmaf(sg1, vr[r], orr);
        float si = fmaf(sg1, vi[r], oii);
        float tr = sr * w1r - si * w1i;
        float ti = sr * w1i + si * w1r;
        orr = __shfl_xor(tr, 2);
        oii = __shfl_xor(ti, 2);
        sr = fmaf(sg2, tr, orr);
        si = fmaf(sg2, ti, oii);
        tr = sr * w2r - si * w2i;
        ti = sr * w2i + si * w2r;
        orr = __shfl_xor(tr, 1);
        oii = __shfl_xor(ti, 1);
        vr[r] = fmaf(sg3, tr, orr);
        vi[r] = fmaf(sg3, ti, oii);
    }
}

// ---------------------------------------------------------------------------
// Kernel 1: Hilbert via register-resident FFT (unchanged from R1)
// ---------------------------------------------------------------------------
__global__ __launch_bounds__(256) void fft_hilbert_kernel(
    const float* __restrict__ x, float2* __restrict__ z)
{
    __shared__ float2 lds[8192];
    const int sig = blockIdx.x;
    const int t = threadIdx.x;
    const int j = t & 7, row = t >> 3;
    const int br3j = ((j & 1) << 2) | (j & 2) | ((j & 4) >> 2);

    float vr[32], vi[32];
    const float* xp = x + (size_t)sig * T_LEN;
    #pragma unroll
    for (int n1 = 0; n1 < 32; ++n1) { vr[n1] = xp[(n1 << 8) + t]; vi[n1] = 0.f; }

    big_fft(vr, vi, lds, t, j, row);

    #pragma unroll
    for (int r = 0; r < 32; ++r) {
        const int k = row + (br5(r) << 5) + (br3j << 10);
        const float h = (k == 0 || k == 4096) ? 1.f : (k < 4096 ? 2.f : 0.f);
        vr[r] = vr[r] * h;
        vi[r] = -vi[r] * h;
    }

    __syncthreads();
    #pragma unroll
    for (int r = 0; r < 32; ++r) {
        int a = row + (br5(r) << 5) + (br3j << 10);
        lds[a ^ (((a >> 10) & 7) << 3)] = make_float2(vr[r], vi[r]);
    }
    __syncthreads();
    #pragma unroll
    for (int n1 = 0; n1 < 32; ++n1) {
        int a = (n1 << 8) + t;
        float2 v = lds[a ^ (((a >> 10) & 7) << 3)];
        vr[n1] = v.x; vi[n1] = v.y;
    }

    big_fft(vr, vi, lds, t, j, row);

    float2* zp = z + (size_t)sig * T_LEN;
    #pragma unroll
    for (int r = 0; r < 32; ++r) {
        float ar = vr[r], ai = -vi[r];
        float inv = rsqrtf(ar * ar + ai * ai);
        float2 o; o.x = ar * inv; o.y = ai * inv;
        zp[(r << 8) + t] = o;
    }
}

// ---------------------------------------------------------------------------
// Kernel 2: partial complex Gram with packed fp32 FMA (unchanged from R1)
// ---------------------------------------------------------------------------
__global__ __launch_bounds__(256) void gram_kernel(
    const float2* __restrict__ z, float* __restrict__ part)
{
    const int b = blockIdx.x, sl = blockIdx.y, tid = threadIdx.x;
    const int q = tid >> 4, p = tid & 15;
    __shared__ vf2 zs[64][65];

    vf2 accp[4][4], acci[4][4];
    #pragma unroll
    for (int a = 0; a < 4; ++a)
        #pragma unroll
        for (int c = 0; c < 4; ++c) { accp[a][c] = 0.f; acci[a][c] = 0.f; }

    const int t0 = sl * (T_LEN / NSLICE);
    for (int chunk = 0; chunk < (T_LEN / NSLICE) / 64; ++chunk) {
        const int tc = t0 + chunk * 64;
        for (int idx = tid; idx < 64 * 64; idx += 256) {
            int rw = idx >> 6, cl = idx & 63;
            float2 v = z[((size_t)b * 64 + rw) * T_LEN + tc + cl];
            vf2 w; w.x = v.x; w.y = v.y;
            zs[rw][cl] = w;
        }
        __syncthreads();
        for (int tt = 0; tt < 64; ++tt) {
            vf2 a2[4], b2[4], bs[4];
            #pragma unroll
            for (int r = 0; r < 4; ++r) a2[r] = zs[q + 16 * r][tt];
            #pragma unroll
            for (int r = 0; r < 4; ++r) { b2[r] = zs[p + 16 * r][tt]; bs[r] = b2[r].yx; }
            #pragma unroll
            for (int ri = 0; ri < 4; ++ri)
                #pragma unroll
                for (int rj = 0; rj < 4; ++rj) {
                    PK_FMA(accp[ri][rj], a2[ri], b2[rj]);
                    PK_FMA(acci[ri][rj], a2[ri], bs[rj]);
                }
        }
        __syncthreads();
    }

    float* pp = part + (size_t)(b * NSLICE + sl) * 4096 * 2;
    #pragma unroll
    for (int ri = 0; ri < 4; ++ri)
        #pragma unroll
        for (int rj = 0; rj < 4; ++rj) {
            int i = q + 16 * ri, jj = p + 16 * rj;
            int e = i * 64 + jj;
            pp[e * 2 + 0] = accp[ri][rj].x + accp[ri][rj].y;
            pp[e * 2 + 1] = acci[ri][rj].y - acci[ri][rj].x;
        }
}

// ---------------------------------------------------------------------------
// Kernel 3: reduce partials, PLV = |G|/T, zero diagonal (unchanged)
// ---------------------------------------------------------------------------
__global__ __launch_bounds__(256) void plv_kernel(
    const float* __restrict__ part, float* __restrict__ out0)
{
    const int b = blockIdx.x, tid = threadIdx.x;
    const float2* pf = (const float2*)part;
    for (int e0 = tid; e0 < 1024; e0 += 256) {
        int e = blockIdx.y * 1024 + e0;
        float gr = 0.f, gi = 0.f;
        for (int s = 0; s < NSLICE; ++s) {
            float2 v = pf[(size_t)(b * NSLICE + s) * 4096 + e];
            gr += v.x; gi += v.y;
        }
        int i = e >> 6, jj = e & 63;
        float val = (i == jj) ? 0.f
                              : sqrtf(gr * gr + gi * gi) * (1.0f / 8192.0f);
        out0[(size_t)b * 4096 + e] = val;
    }
}

// ---------------------------------------------------------------------------
// Kernel 4 (REWRITTEN): GCN + MHA, 1024 threads (16 waves), wave-per-row
// mapping, heads parallel across waves (2 waves/head). 64 KB arena:
//   [0..4095]      conn -> h2 (in-place, per-wave-safe) -> oh
//   [4096..8191]   M -> P -> q
//   [8192..16383]  h1 -> k,v ; after k hoisted: sc slots; then opw (s65)
// Weights (emb,w1,w2,ipw) stream from global (L1/L2-hot, all blocks share).
// ---------------------------------------------------------------------------
__global__ __launch_bounds__(1024) void gnn_mha_kernel(
    const float* __restrict__ conn, const float* __restrict__ emb,
    const float* __restrict__ w1,   const float* __restrict__ b1,
    const float* __restrict__ w2,   const float* __restrict__ b2,
    const float* __restrict__ ipw,  const float* __restrict__ ipb,
    const float* __restrict__ opw,  const float* __restrict__ opb,
    float* __restrict__ out1, float* __restrict__ out2)
{
    __shared__ float S[16384];
    const int b = blockIdx.x, tid = threadIdx.x;
    const int lane = tid & 63, w = tid >> 6;   // 16 waves
    const int i0 = w * 4;                       // 4 rows per wave

    // phase 1: conn -> S[0..4095]
    for (int e = tid; e < 4096; e += 1024) S[e] = conn[(size_t)b * 4096 + e];
    __syncthreads();

    // phase 2: M = conn @ emb -> S[4096..]
    {
        float acc[4] = {0.f, 0.f, 0.f, 0.f};
        #pragma unroll 8
        for (int k = 0; k < 64; ++k) {
            float ev = emb[k * 64 + lane];
            #pragma unroll
            for (int r = 0; r < 4; ++r)
                acc[r] = fmaf(S[(i0 + r) * 64 + k], ev, acc[r]);
        }
        #pragma unroll
        for (int r = 0; r < 4; ++r) S[4096 + (i0 + r) * 64 + lane] = acc[r];
    }
    __syncthreads();

    // phase 3: h1 = relu(M @ w1 + b1) -> S[8192..] (64x128)
    {
        float a0[4] = {0.f, 0.f, 0.f, 0.f}, a1[4] = {0.f, 0.f, 0.f, 0.f};
        #pragma unroll 8
        for (int k = 0; k < 64; ++k) {
            float wa = w1[k * 128 + lane];
            float wb = w1[k * 128 + 64 + lane];
            #pragma unroll
            for (int r = 0; r < 4; ++r) {
                float m = S[4096 + (i0 + r) * 64 + k];
                a0[r] = fmaf(m, wa, a0[r]);
                a1[r] = fmaf(m, wb, a1[r]);
            }
        }
        float bb0 = b1[lane], bb1 = b1[64 + lane];
        #pragma unroll
        for (int r = 0; r < 4; ++r) {
            S[8192 + (i0 + r) * 128 + lane]      = fmaxf(a0[r] + bb0, 0.f);
            S[8192 + (i0 + r) * 128 + 64 + lane] = fmaxf(a1[r] + bb1, 0.f);
        }
    }
    __syncthreads();

    // phase 4: P = h1 @ w2 -> S[4096..] (M dead)
    {
        float acc[4] = {0.f, 0.f, 0.f, 0.f};
        #pragma unroll 8
        for (int c = 0; c < 128; ++c) {
            float wv = w2[c * 64 + lane];
            #pragma unroll
            for (int r = 0; r < 4; ++r)
                acc[r] = fmaf(S[8192 + (i0 + r) * 128 + c], wv, acc[r]);
        }
        __syncthreads();   // all h1 reads done before overwriting M area
        #pragma unroll
        for (int r = 0; r < 4; ++r) S[4096 + (i0 + r) * 64 + lane] = acc[r];
    }
    __syncthreads();

    // phase 5: h2 = conn @ P + b2 -> in-place over conn rows (own rows only)
    {
        float acc[4] = {0.f, 0.f, 0.f, 0.f};
        #pragma unroll 8
        for (int k = 0; k < 64; ++k) {
            float pv = S[4096 + k * 64 + lane];
            #pragma unroll
            for (int r = 0; r < 4; ++r)
                acc[r] = fmaf(S[(i0 + r) * 64 + k], pv, acc[r]);
        }
        float bb = b2[lane];
        #pragma unroll
        for (int r = 0; r < 4; ++r) {
            float v = acc[r] + bb;
            S[(i0 + r) * 64 + lane] = v;                       // h2
            out2[(size_t)b * 4096 + (i0 + r) * 64 + lane] = v; // output 2
        }
    }
    __syncthreads();

    // phase 6: qkv = h2 @ ipw^T + ipb -> q@4096, k@8192, v@12288
    {
        float aq[4] = {0.f, 0.f, 0.f, 0.f};
        float ak[4] = {0.f, 0.f, 0.f, 0.f};
        float av[4] = {0.f, 0.f, 0.f, 0.f};
        #pragma unroll 8
        for (int k = 0; k < 64; ++k) {
            float wq = ipw[lane * 64 + k];
            float wk = ipw[(64 + lane) * 64 + k];
            float wv = ipw[(128 + lane) * 64 + k];
            #pragma unroll
            for (int r = 0; r < 4; ++r) {
                float hv = S[(i0 + r) * 64 + k];
                aq[r] = fmaf(hv, wq, aq[r]);
                ak[r] = fmaf(hv, wk, ak[r]);
                av[r] = fmaf(hv, wv, av[r]);
            }
        }
        float bq = ipb[lane], bk = ipb[64 + lane], bv = ipb[128 + lane];
        __syncthreads();   // all h1/P-area readers done (P dead; h1 dead)
        #pragma unroll
        for (int r = 0; r < 4; ++r) {
            S[4096  + (i0 + r) * 64 + lane] = aq[r] + bq;
            S[8192  + (i0 + r) * 64 + lane] = ak[r] + bk;
            S[12288 + (i0 + r) * 64 + lane] = av[r] + bv;
        }
    }
    __syncthreads();

    // phase 7: hoist this head's K column-slice into registers (lane = m)
    const int h = w >> 1;
    float kk[8];
    #pragma unroll
    for (int d = 0; d < 8; ++d) kk[d] = S[8192 + lane * 64 + h * 8 + d];
    __syncthreads();   // k area -> sc scratch

    // phase 8: per-row scores + softmax + attn@V; oh -> S[0..] (h2 dead)
    {
        const float iscale = 0.35355339059327373f;  // 1/sqrt(8)
        const int mc = lane >> 3, dd = lane & 7;
        for (int rr = 0; rr < 32; ++rr) {
            const int n = (w & 1) * 32 + rr;
            float s = 0.f;
            #pragma unroll
            for (int d = 0; d < 8; ++d)
                s = fmaf(S[4096 + n * 64 + h * 8 + d], kk[d], s);
            s *= iscale;
            float mx = s;
            #pragma unroll
            for (int off = 1; off < 64; off <<= 1)
                mx = fmaxf(mx, __shfl_xor(mx, off));
            float ev = __expf(s - mx);
            float sum = ev;
            #pragma unroll
            for (int off = 1; off < 64; off <<= 1)
                sum += __shfl_xor(sum, off);
            S[8192 + w * 68 + lane] = ev / sum;   // per-wave private slot
            float o = 0.f;
            #pragma unroll
            for (int jx = 0; jx < 8; ++jx)
                o = fmaf(S[8192 + w * 68 + mc * 8 + jx],
                         S[12288 + (mc * 8 + jx) * 64 + h * 8 + dd], o);
            o += __shfl_xor(o, 8);
            o += __shfl_xor(o, 16);
            o += __shfl_xor(o, 32);
            if (lane < 8) S[n * 64 + h * 8 + lane] = o;   // oh
        }
    }
    __syncthreads();

    // phase 9: stage opw with stride-65 padding into S[8192..] (k,v,sc dead)
    for (int e = tid; e < 4096; e += 1024) {
        int r = e >> 6, c = e & 63;
        S[8192 + r * 65 + c] = opw[e];
    }
    __syncthreads();

    // phase 10: out1 = oh @ opw^T + opb
    {
        float acc[4] = {0.f, 0.f, 0.f, 0.f};
        #pragma unroll 8
        for (int c = 0; c < 64; ++c) {
            float wv = S[8192 + lane * 65 + c];
            #pragma unroll
            for (int r = 0; r < 4; ++r)
                acc[r] = fmaf(S[(i0 + r) * 64 + c], wv, acc[r]);
        }
        float ob = opb[lane];
        #pragma unroll
        for (int r = 0; r < 4; ++r)
            out1[(size_t)b * 4096 + (i0 + r) * 64 + lane] = acc[r] + ob;
    }
}

// ---------------------------------------------------------------------------
extern "C" void kernel_launch(void* const* d_in, const int* in_sizes, int n_in,
                              void* d_out, int out_size, void* d_ws, size_t ws_size,
                              hipStream_t stream)
{
    const float* x   = (const float*)d_in[0];
    const float* emb = (const float*)d_in[1];
    const float* w1  = (const float*)d_in[2];
    const float* b1  = (const float*)d_in[3];
    const float* w2  = (const float*)d_in[4];
    const float* b2  = (const float*)d_in[5];
    const float* ipw = (const float*)d_in[6];
    const float* ipb = (const float*)d_in[7];
    const float* opw = (const float*)d_in[8];
    const float* opb = (const float*)d_in[9];

    float* out  = (float*)d_out;
    float* out0 = out;
    float* out1 = out + 131072;
    float* out2 = out + 262144;

    float2* z   = (float2*)d_ws;
    float* part = (float*)((char*)d_ws + (size_t)32 * 64 * 8192 * 8);

    hipLaunchKernelGGL(fft_hilbert_kernel, dim3(32 * 64), dim3(256), 0, stream,
                       x, z);
    hipLaunchKernelGGL(gram_kernel, dim3(32, NSLICE), dim3(256), 0, stream,
                       z, part);
    hipLaunchKernelGGL(plv_kernel, dim3(32, 4), dim3(256), 0, stream, part, out0);
    hipLaunchKernelGGL(gnn_mha_kernel, dim3(32), dim3(1024), 0, stream,
                       out0, emb, w1, b1, w2, b2, ipw, ipb, opw, opb,
                       out1, out2);
}

// Round 4
// 411.628 us; speedup vs baseline: 1.8127x; 1.1162x over previous
//
#include <hip/hip_runtime.h>
#include <math.h>

#define T_LEN 8192
#define NS_G 8   // gram K-slices

typedef float  f32x4 __attribute__((ext_vector_type(4)));
typedef _Float16 f16x8 __attribute__((ext_vector_type(8)));

__device__ __forceinline__ constexpr int br5(int r) {
    return ((r & 1) << 4) | ((r & 2) << 2) | (r & 4) | ((r & 8) >> 2) | ((r & 16) >> 4);
}

// in-register 32-point DIF FFT; output slot r holds bin br5(r)
__device__ __forceinline__ void fft32(float* vr, float* vi)
{
    constexpr float TR[16] = {
        1.0f, 0.9807852804f, 0.9238795325f, 0.8314696123f,
        0.7071067812f, 0.5555702330f, 0.3826834324f, 0.1950903220f,
        0.0f, -0.1950903220f, -0.3826834324f, -0.5555702330f,
        -0.7071067812f, -0.8314696123f, -0.9238795325f, -0.9807852804f };
    constexpr float TI[16] = {
        0.0f, -0.1950903220f, -0.3826834324f, -0.5555702330f,
        -0.7071067812f, -0.8314696123f, -0.9238795325f, -0.9807852804f,
        -1.0f, -0.9807852804f, -0.9238795325f, -0.8314696123f,
        -0.7071067812f, -0.5555702330f, -0.3826834324f, -0.1950903220f };
    #pragma unroll
    for (int s = 0; s < 5; ++s) {
        const int half = 16 >> s;
        #pragma unroll
        for (int g = 0; g < (1 << s); ++g) {
            #pragma unroll
            for (int jj = 0; jj < half; ++jj) {
                const int i1 = g * (half << 1) + jj;
                const int i2 = i1 + half;
                const int q = jj << s;
                float ar = vr[i1], ai = vi[i1];
                float br = vr[i2], bi = vi[i2];
                vr[i1] = ar + br; vi[i1] = ai + bi;
                float dr = ar - br, di = ai - bi;
                vr[i2] = dr * TR[q] - di * TI[q];
                vi[i2] = dr * TI[q] + di * TR[q];
            }
        }
    }
}

__device__ __forceinline__ int swz1(int a) { return a ^ (((a >> 8) & 3) << 3); }

// 8192-pt forward FFT; 32 KB LDS (float), transposes in re/im passes.
// Output: slot r of thread t holds bin k = (t>>3) + 32*br5(r) + 1024*br3(t&7).
__device__ __forceinline__ void big_fft(float* vr, float* vi, float* lds,
                                        int t, int j, int row)
{
    fft32(vr, vi);
    const float base1 = -7.669903939428206e-4f * (float)t;   // -2pi/8192 * t
    #pragma unroll
    for (int r = 0; r < 32; ++r) {
        const int k1 = br5(r);
        if (k1) {
            float c, s; __sincosf(base1 * (float)k1, &s, &c);
            float xr = vr[r], xi = vi[r];
            vr[r] = xr * c - xi * s;
            vi[r] = xr * s + xi * c;
        }
    }
    // transpose via LDS, two passes (re, im)
    __syncthreads();
    #pragma unroll
    for (int r = 0; r < 32; ++r) lds[swz1((br5(r) << 8) + t)] = vr[r];
    __syncthreads();
    #pragma unroll
    for (int m1 = 0; m1 < 32; ++m1)
        vr[m1] = lds[swz1((row << 8) + (m1 << 3) + j)];
    __syncthreads();
    #pragma unroll
    for (int r = 0; r < 32; ++r) lds[swz1((br5(r) << 8) + t)] = vi[r];
    __syncthreads();
    #pragma unroll
    for (int m1 = 0; m1 < 32; ++m1)
        vi[m1] = lds[swz1((row << 8) + (m1 << 3) + j)];

    fft32(vr, vi);
    const float base2 = -0.02454369260617026f * (float)j;     // -2pi/256 * j
    #pragma unroll
    for (int r = 0; r < 32; ++r) {
        const int k1p = br5(r);
        if (k1p) {
            float c, s; __sincosf(base2 * (float)k1p, &s, &c);
            float xr = vr[r], xi = vi[r];
            vr[r] = xr * c - xi * s;
            vi[r] = xr * s + xi * c;
        }
    }
    // cross-lane FFT_8 over j (DIF; output lane j holds bin br3(j))
    const float R2 = 0.7071067811865475f;
    const int jm = j & 3;
    float w1r = 1.f, w1i = 0.f;
    if (j >= 4) {
        w1r = (jm == 0) ? 1.f : (jm == 1) ? R2 : (jm == 2) ? 0.f : -R2;
        w1i = (jm == 0) ? 0.f : (jm == 1) ? -R2 : (jm == 2) ? -1.f : -R2;
    }
    const float sg1 = (j < 4) ? 1.f : -1.f;
    const float sg2 = (j & 2) ? -1.f : 1.f;
    const bool tw2 = (j & 2) && (j & 1);
    const float w2r = tw2 ? 0.f : 1.f;
    const float w2i = tw2 ? -1.f : 0.f;
    const float sg3 = (j & 1) ? -1.f : 1.f;
    #pragma unroll
    for (int r = 0; r < 32; ++r) {
        float orr = __shfl_xor(vr[r], 4);
        float oii = __shfl_xor(vi[r], 4);
        float sr = fmaf(sg1, vr[r], orr);
        float si = fmaf(sg1, vi[r], oii);
        float tr = sr * w1r - si * w1i;
        float ti = sr * w1i + si * w1r;
        orr = __shfl_xor(tr, 2);
        oii = __shfl_xor(ti, 2);
        sr = fmaf(sg2, tr, orr);
        si = fmaf(sg2, ti, oii);
        tr = sr * w2r - si * w2i;
        ti = sr * w2i + si * w2r;
        orr = __shfl_xor(tr, 1);
        oii = __shfl_xor(ti, 1);
        vr[r] = fmaf(sg3, tr, orr);
        vi[r] = fmaf(sg3, ti, oii);
    }
}

// ---------------------------------------------------------------------------
// Kernel 1: Hilbert via register FFT; writes unit phasors as f16 planes.
// ---------------------------------------------------------------------------
__global__ __launch_bounds__(256, 3) void fft_hilbert_kernel(
    const float* __restrict__ x, _Float16* __restrict__ zr,
    _Float16* __restrict__ zi)
{
    __shared__ float lds[8192];   // 32 KB
    const int sig = blockIdx.x;
    const int t = threadIdx.x;
    const int j = t & 7, row = t >> 3;
    const int br3j = ((j & 1) << 2) | (j & 2) | ((j & 4) >> 2);

    float vr[32], vi[32];
    const float* xp = x + (size_t)sig * T_LEN;
    #pragma unroll
    for (int n1 = 0; n1 < 32; ++n1) { vr[n1] = xp[(n1 << 8) + t]; vi[n1] = 0.f; }

    big_fft(vr, vi, lds, t, j, row);

    // conj + Hilbert filter
    #pragma unroll
    for (int r = 0; r < 32; ++r) {
        const int k = row + (br5(r) << 5) + (br3j << 10);
        const float h = (k == 0 || k == 4096) ? 1.f : (k < 4096 ? 2.f : 0.f);
        vr[r] = vr[r] * h;
        vi[r] = -vi[r] * h;
    }

    // redistribute to natural order, two passes
    __syncthreads();
    #pragma unroll
    for (int r = 0; r < 32; ++r) {
        int a = row + (br5(r) << 5) + (br3j << 10);
        lds[a ^ (((a >> 10) & 3) << 3)] = vr[r];
    }
    __syncthreads();
    #pragma unroll
    for (int n1 = 0; n1 < 32; ++n1) {
        int a = (n1 << 8) + t;
        vr[n1] = lds[a ^ (((a >> 10) & 3) << 3)];
    }
    __syncthreads();
    #pragma unroll
    for (int r = 0; r < 32; ++r) {
        int a = row + (br5(r) << 5) + (br3j << 10);
        lds[a ^ (((a >> 10) & 3) << 3)] = vi[r];
    }
    __syncthreads();
    #pragma unroll
    for (int n1 = 0; n1 < 32; ++n1) {
        int a = (n1 << 8) + t;
        vi[n1] = lds[a ^ (((a >> 10) & 3) << 3)];
    }

    big_fft(vr, vi, lds, t, j, row);

    // conj + normalize; store f16 planes (fixed t-permutation, PLV-invariant)
    _Float16* zrp = zr + (size_t)sig * T_LEN;
    _Float16* zip = zi + (size_t)sig * T_LEN;
    #pragma unroll
    for (int r = 0; r < 32; ++r) {
        float ar = vr[r], ai = -vi[r];
        float inv = rsqrtf(ar * ar + ai * ai);
        zrp[(r << 8) + t] = (_Float16)(ar * inv);
        zip[(r << 8) + t] = (_Float16)(ai * inv);
    }
}

// ---------------------------------------------------------------------------
// Kernel 2: Gram via f16 MFMA. G_re = Re*Re^T + Im*Im^T,
// G_im = Im*Re^T - Re*Im^T. Both operands are rows.rows^T so A- and B-frags
// load identically. Grid (32 batches, NS_G k-slices), 256 thr (4 waves),
// wave w owns output rows 16w..16w+15 (4 tiles of 16x16).
// ---------------------------------------------------------------------------
#define GS 72   // LDS row stride in f16 (64 + 8 pad)
__global__ __launch_bounds__(256) void gram_kernel(
    const _Float16* __restrict__ zr, const _Float16* __restrict__ zi,
    float* __restrict__ part)
{
    __shared__ _Float16 ReS[64 * GS];
    __shared__ _Float16 ImS[64 * GS];
    const int b = blockIdx.x, sl = blockIdx.y, tid = threadIdx.x;
    const int w = tid >> 6, lane = tid & 63;
    const int mrow = lane & 15, quad = lane >> 4;

    f32x4 acc_re[4], acc_i1[4], acc_i2[4];
    #pragma unroll
    for (int tn = 0; tn < 4; ++tn) {
        acc_re[tn] = (f32x4)0.f; acc_i1[tn] = (f32x4)0.f; acc_i2[tn] = (f32x4)0.f;
    }

    const int k0 = sl * (T_LEN / NS_G);
    for (int chunk = 0; chunk < (T_LEN / NS_G) / 64; ++chunk) {
        const size_t gbase = (size_t)b * 64 * T_LEN + k0 + chunk * 64;
        __syncthreads();
        // stage 64 rows x 64 k of both planes (uint4 = 8 f16)
        for (int pass = 0; pass < 2; ++pass) {
            int rw = (tid >> 3) + pass * 32;
            int c8 = (tid & 7) * 8;
            *(uint4*)&ReS[rw * GS + c8] = *(const uint4*)&zr[gbase + (size_t)rw * T_LEN + c8];
            *(uint4*)&ImS[rw * GS + c8] = *(const uint4*)&zi[gbase + (size_t)rw * T_LEN + c8];
        }
        __syncthreads();
        #pragma unroll
        for (int ks = 0; ks < 2; ++ks) {
            const int koff = ks * 32 + quad * 8;
            f16x8 a_re = *(f16x8*)&ReS[(w * 16 + mrow) * GS + koff];
            f16x8 a_im = *(f16x8*)&ImS[(w * 16 + mrow) * GS + koff];
            #pragma unroll
            for (int tn = 0; tn < 4; ++tn) {
                f16x8 b_re = *(f16x8*)&ReS[(tn * 16 + mrow) * GS + koff];
                f16x8 b_im = *(f16x8*)&ImS[(tn * 16 + mrow) * GS + koff];
                acc_re[tn] = __builtin_amdgcn_mfma_f32_16x16x32_f16(a_re, b_re, acc_re[tn], 0, 0, 0);
                acc_re[tn] = __builtin_amdgcn_mfma_f32_16x16x32_f16(a_im, b_im, acc_re[tn], 0, 0, 0);
                acc_i1[tn] = __builtin_amdgcn_mfma_f32_16x16x32_f16(a_im, b_re, acc_i1[tn], 0, 0, 0);
                acc_i2[tn] = __builtin_amdgcn_mfma_f32_16x16x32_f16(a_re, b_im, acc_i2[tn], 0, 0, 0);
            }
        }
    }

    // C/D layout: col = lane&15, row = quad*4 + reg
    float2* pp = (float2*)part + (size_t)(b * NS_G + sl) * 4096;
    #pragma unroll
    for (int tn = 0; tn < 4; ++tn)
        #pragma unroll
        for (int reg = 0; reg < 4; ++reg) {
            int m = w * 16 + quad * 4 + reg;
            int n = tn * 16 + mrow;
            float2 v;
            v.x = acc_re[tn][reg];
            v.y = acc_i1[tn][reg] - acc_i2[tn][reg];
            pp[m * 64 + n] = v;
        }
}

// ---------------------------------------------------------------------------
// Kernel 3: reduce partials, PLV = |G|/T, zero diagonal
// ---------------------------------------------------------------------------
__global__ __launch_bounds__(256) void plv_kernel(
    const float* __restrict__ part, float* __restrict__ out0)
{
    const int b = blockIdx.x, tid = threadIdx.x;
    const float2* pf = (const float2*)part;
    for (int e0 = tid; e0 < 1024; e0 += 256) {
        int e = blockIdx.y * 1024 + e0;
        float gr = 0.f, gi = 0.f;
        #pragma unroll
        for (int s = 0; s < NS_G; ++s) {
            float2 v = pf[(size_t)(b * NS_G + s) * 4096 + e];
            gr += v.x; gi += v.y;
        }
        int i = e >> 6, jj = e & 63;
        float val = (i == jj) ? 0.f
                              : sqrtf(gr * gr + gi * gi) * (1.0f / 8192.0f);
        out0[(size_t)b * 4096 + e] = val;
    }
}

// ---------------------------------------------------------------------------
// Kernel 4: GCN + MHA (unchanged from R2)
// ---------------------------------------------------------------------------
__global__ __launch_bounds__(1024) void gnn_mha_kernel(
    const float* __restrict__ conn, const float* __restrict__ emb,
    const float* __restrict__ w1,   const float* __restrict__ b1,
    const float* __restrict__ w2,   const float* __restrict__ b2,
    const float* __restrict__ ipw,  const float* __restrict__ ipb,
    const float* __restrict__ opw,  const float* __restrict__ opb,
    float* __restrict__ out1, float* __restrict__ out2)
{
    __shared__ float S[16384];
    const int b = blockIdx.x, tid = threadIdx.x;
    const int lane = tid & 63, w = tid >> 6;
    const int i0 = w * 4;

    for (int e = tid; e < 4096; e += 1024) S[e] = conn[(size_t)b * 4096 + e];
    __syncthreads();

    {   // M = conn @ emb
        float acc[4] = {0.f, 0.f, 0.f, 0.f};
        #pragma unroll 8
        for (int k = 0; k < 64; ++k) {
            float ev = emb[k * 64 + lane];
            #pragma unroll
            for (int r = 0; r < 4; ++r)
                acc[r] = fmaf(S[(i0 + r) * 64 + k], ev, acc[r]);
        }
        #pragma unroll
        for (int r = 0; r < 4; ++r) S[4096 + (i0 + r) * 64 + lane] = acc[r];
    }
    __syncthreads();

    {   // h1 = relu(M @ w1 + b1)
        float a0[4] = {0.f, 0.f, 0.f, 0.f}, a1[4] = {0.f, 0.f, 0.f, 0.f};
        #pragma unroll 8
        for (int k = 0; k < 64; ++k) {
            float wa = w1[k * 128 + lane];
            float wb = w1[k * 128 + 64 + lane];
            #pragma unroll
            for (int r = 0; r < 4; ++r) {
                float m = S[4096 + (i0 + r) * 64 + k];
                a0[r] = fmaf(m, wa, a0[r]);
                a1[r] = fmaf(m, wb, a1[r]);
            }
        }
        float bb0 = b1[lane], bb1 = b1[64 + lane];
        #pragma unroll
        for (int r = 0; r < 4; ++r) {
            S[8192 + (i0 + r) * 128 + lane]      = fmaxf(a0[r] + bb0, 0.f);
            S[8192 + (i0 + r) * 128 + 64 + lane] = fmaxf(a1[r] + bb1, 0.f);
        }
    }
    __syncthreads();

    {   // P = h1 @ w2
        float acc[4] = {0.f, 0.f, 0.f, 0.f};
        #pragma unroll 8
        for (int c = 0; c < 128; ++c) {
            float wv = w2[c * 64 + lane];
            #pragma unroll
            for (int r = 0; r < 4; ++r)
                acc[r] = fmaf(S[8192 + (i0 + r) * 128 + c], wv, acc[r]);
        }
        __syncthreads();
        #pragma unroll
        for (int r = 0; r < 4; ++r) S[4096 + (i0 + r) * 64 + lane] = acc[r];
    }
    __syncthreads();

    {   // h2 = conn @ P + b2 (in-place over conn rows)
        float acc[4] = {0.f, 0.f, 0.f, 0.f};
        #pragma unroll 8
        for (int k = 0; k < 64; ++k) {
            float pv = S[4096 + k * 64 + lane];
            #pragma unroll
            for (int r = 0; r < 4; ++r)
                acc[r] = fmaf(S[(i0 + r) * 64 + k], pv, acc[r]);
        }
        float bb = b2[lane];
        #pragma unroll
        for (int r = 0; r < 4; ++r) {
            float v = acc[r] + bb;
            S[(i0 + r) * 64 + lane] = v;
            out2[(size_t)b * 4096 + (i0 + r) * 64 + lane] = v;
        }
    }
    __syncthreads();

    {   // qkv
        float aq[4] = {0.f, 0.f, 0.f, 0.f};
        float ak[4] = {0.f, 0.f, 0.f, 0.f};
        float av[4] = {0.f, 0.f, 0.f, 0.f};
        #pragma unroll 8
        for (int k = 0; k < 64; ++k) {
            float wq = ipw[lane * 64 + k];
            float wk = ipw[(64 + lane) * 64 + k];
            float wv = ipw[(128 + lane) * 64 + k];
            #pragma unroll
            for (int r = 0; r < 4; ++r) {
                float hv = S[(i0 + r) * 64 + k];
                aq[r] = fmaf(hv, wq, aq[r]);
                ak[r] = fmaf(hv, wk, ak[r]);
                av[r] = fmaf(hv, wv, av[r]);
            }
        }
        float bq = ipb[lane], bk = ipb[64 + lane], bv = ipb[128 + lane];
        __syncthreads();
        #pragma unroll
        for (int r = 0; r < 4; ++r) {
            S[4096  + (i0 + r) * 64 + lane] = aq[r] + bq;
            S[8192  + (i0 + r) * 64 + lane] = ak[r] + bk;
            S[12288 + (i0 + r) * 64 + lane] = av[r] + bv;
        }
    }
    __syncthreads();

    const int h = w >> 1;
    float kk[8];
    #pragma unroll
    for (int d = 0; d < 8; ++d) kk[d] = S[8192 + lane * 64 + h * 8 + d];
    __syncthreads();

    {   // scores + softmax + attn@V
        const float iscale = 0.35355339059327373f;
        const int mc = lane >> 3, dd = lane & 7;
        for (int rr = 0; rr < 32; ++rr) {
            const int n = (w & 1) * 32 + rr;
            float s = 0.f;
            #pragma unroll
            for (int d = 0; d < 8; ++d)
                s = fmaf(S[4096 + n * 64 + h * 8 + d], kk[d], s);
            s *= iscale;
            float mx = s;
            #pragma unroll
            for (int off = 1; off < 64; off <<= 1)
                mx = fmaxf(mx, __shfl_xor(mx, off));
            float ev = __expf(s - mx);
            float sum = ev;
            #pragma unroll
            for (int off = 1; off < 64; off <<= 1)
                sum += __shfl_xor(sum, off);
            S[8192 + w * 68 + lane] = ev / sum;
            float o = 0.f;
            #pragma unroll
            for (int jx = 0; jx < 8; ++jx)
                o = fmaf(S[8192 + w * 68 + mc * 8 + jx],
                         S[12288 + (mc * 8 + jx) * 64 + h * 8 + dd], o);
            o += __shfl_xor(o, 8);
            o += __shfl_xor(o, 16);
            o += __shfl_xor(o, 32);
            if (lane < 8) S[n * 64 + h * 8 + lane] = o;
        }
    }
    __syncthreads();

    for (int e = tid; e < 4096; e += 1024) {
        int r = e >> 6, c = e & 63;
        S[8192 + r * 65 + c] = opw[e];
    }
    __syncthreads();

    {   // out1 = oh @ opw^T + opb
        float acc[4] = {0.f, 0.f, 0.f, 0.f};
        #pragma unroll 8
        for (int c = 0; c < 64; ++c) {
            float wv = S[8192 + lane * 65 + c];
            #pragma unroll
            for (int r = 0; r < 4; ++r)
                acc[r] = fmaf(S[(i0 + r) * 64 + c], wv, acc[r]);
        }
        float ob = opb[lane];
        #pragma unroll
        for (int r = 0; r < 4; ++r)
            out1[(size_t)b * 4096 + (i0 + r) * 64 + lane] = acc[r] + ob;
    }
}

// ---------------------------------------------------------------------------
extern "C" void kernel_launch(void* const* d_in, const int* in_sizes, int n_in,
                              void* d_out, int out_size, void* d_ws, size_t ws_size,
                              hipStream_t stream)
{
    const float* x   = (const float*)d_in[0];
    const float* emb = (const float*)d_in[1];
    const float* w1  = (const float*)d_in[2];
    const float* b1  = (const float*)d_in[3];
    const float* w2  = (const float*)d_in[4];
    const float* b2  = (const float*)d_in[5];
    const float* ipw = (const float*)d_in[6];
    const float* ipb = (const float*)d_in[7];
    const float* opw = (const float*)d_in[8];
    const float* opb = (const float*)d_in[9];

    float* out  = (float*)d_out;
    float* out0 = out;
    float* out1 = out + 131072;
    float* out2 = out + 262144;

    _Float16* zr = (_Float16*)d_ws;                     // 32 MB
    _Float16* zi = zr + (size_t)2048 * T_LEN;           // 32 MB
    float* part  = (float*)(zi + (size_t)2048 * T_LEN); // 8 MB

    hipLaunchKernelGGL(fft_hilbert_kernel, dim3(32 * 64), dim3(256), 0, stream,
                       x, zr, zi);
    hipLaunchKernelGGL(gram_kernel, dim3(32, NS_G), dim3(256), 0, stream,
                       zr, zi, part);
    hipLaunchKernelGGL(plv_kernel, dim3(32, 4), dim3(256), 0, stream, part, out0);
    hipLaunchKernelGGL(gnn_mha_kernel, dim3(32), dim3(1024), 0, stream,
                       out0, emb, w1, b1, w2, b2, ipw, ipb, opw, opb,
                       out1, out2);
}

// Round 5
// 388.311 us; speedup vs baseline: 1.9215x; 1.0600x over previous
//
#include <hip/hip_runtime.h>
#include <math.h>

#define T_LEN 8192
#define NS_G 8   // gram K-slices

typedef float  f32x4 __attribute__((ext_vector_type(4)));
typedef _Float16 f16x8 __attribute__((ext_vector_type(8)));

__device__ __forceinline__ constexpr int br5(int r) {
    return ((r & 1) << 4) | ((r & 2) << 2) | (r & 4) | ((r & 8) >> 2) | ((r & 16) >> 4);
}

// in-register 32-point DIF FFT; output slot r holds bin br5(r)
__device__ __forceinline__ void fft32(float* vr, float* vi)
{
    constexpr float TR[16] = {
        1.0f, 0.9807852804f, 0.9238795325f, 0.8314696123f,
        0.7071067812f, 0.5555702330f, 0.3826834324f, 0.1950903220f,
        0.0f, -0.1950903220f, -0.3826834324f, -0.5555702330f,
        -0.7071067812f, -0.8314696123f, -0.9238795325f, -0.9807852804f };
    constexpr float TI[16] = {
        0.0f, -0.1950903220f, -0.3826834324f, -0.5555702330f,
        -0.7071067812f, -0.8314696123f, -0.9238795325f, -0.9807852804f,
        -1.0f, -0.9807852804f, -0.9238795325f, -0.8314696123f,
        -0.7071067812f, -0.5555702330f, -0.3826834324f, -0.1950903220f };
    #pragma unroll
    for (int s = 0; s < 5; ++s) {
        const int half = 16 >> s;
        #pragma unroll
        for (int g = 0; g < (1 << s); ++g) {
            #pragma unroll
            for (int jj = 0; jj < half; ++jj) {
                const int i1 = g * (half << 1) + jj;
                const int i2 = i1 + half;
                const int q = jj << s;
                float ar = vr[i1], ai = vi[i1];
                float br = vr[i2], bi = vi[i2];
                vr[i1] = ar + br; vi[i1] = ai + bi;
                float dr = ar - br, di = ai - bi;
                vr[i2] = dr * TR[q] - di * TI[q];
                vi[i2] = dr * TI[q] + di * TR[q];
            }
        }
    }
}

// apply twiddle w^k1 (k1=1..31) to slot br5(k1) via iterative rotation chain;
// bit-reversal is an involution so all indices are compile-time constants.
__device__ __forceinline__ void twiddle_chain(float* vr, float* vi, float ang)
{
    float c1, s1;
    __sincosf(ang, &s1, &c1);
    float cw = 1.f, sw = 0.f;
    #pragma unroll
    for (int k1 = 1; k1 < 32; ++k1) {
        float t0 = cw * c1 - sw * s1;
        sw = cw * s1 + sw * c1;
        cw = t0;
        const int r = br5(k1);
        float xr = vr[r], xi = vi[r];
        vr[r] = xr * cw - xi * sw;
        vi[r] = xr * sw + xi * cw;
    }
}

__device__ __forceinline__ int swz1(int a) { return a ^ (((a >> 8) & 3) << 3); }

// 8192-pt forward FFT; 32 KB LDS (float), transposes in re/im passes.
// Output: slot r of thread t holds bin k = (t>>3) + 32*br5(r) + 1024*br3(t&7).
__device__ __forceinline__ void big_fft(float* vr, float* vi, float* lds,
                                        int t, int j, int row)
{
    fft32(vr, vi);
    twiddle_chain(vr, vi, -7.669903939428206e-4f * (float)t);   // -2pi/8192 * t

    // transpose via LDS, two passes (re, im)
    __syncthreads();
    #pragma unroll
    for (int r = 0; r < 32; ++r) lds[swz1((br5(r) << 8) + t)] = vr[r];
    __syncthreads();
    #pragma unroll
    for (int m1 = 0; m1 < 32; ++m1)
        vr[m1] = lds[swz1((row << 8) + (m1 << 3) + j)];
    __syncthreads();
    #pragma unroll
    for (int r = 0; r < 32; ++r) lds[swz1((br5(r) << 8) + t)] = vi[r];
    __syncthreads();
    #pragma unroll
    for (int m1 = 0; m1 < 32; ++m1)
        vi[m1] = lds[swz1((row << 8) + (m1 << 3) + j)];

    fft32(vr, vi);
    twiddle_chain(vr, vi, -0.02454369260617026f * (float)j);    // -2pi/256 * j

    // cross-lane FFT_8 over j (DIF; output lane j holds bin br3(j))
    const float R2 = 0.7071067811865475f;
    const int jm = j & 3;
    float w1r = 1.f, w1i = 0.f;
    if (j >= 4) {
        w1r = (jm == 0) ? 1.f : (jm == 1) ? R2 : (jm == 2) ? 0.f : -R2;
        w1i = (jm == 0) ? 0.f : (jm == 1) ? -R2 : (jm == 2) ? -1.f : -R2;
    }
    const float sg1 = (j < 4) ? 1.f : -1.f;
    const float sg2 = (j & 2) ? -1.f : 1.f;
    const bool tw2 = (j & 2) && (j & 1);
    const float w2r = tw2 ? 0.f : 1.f;
    const float w2i = tw2 ? -1.f : 0.f;
    const float sg3 = (j & 1) ? -1.f : 1.f;
    #pragma unroll
    for (int r = 0; r < 32; ++r) {
        float orr = __shfl_xor(vr[r], 4);
        float oii = __shfl_xor(vi[r], 4);
        float sr = fmaf(sg1, vr[r], orr);
        float si = fmaf(sg1, vi[r], oii);
        float tr = sr * w1r - si * w1i;
        float ti = sr * w1i + si * w1r;
        orr = __shfl_xor(tr, 2);
        oii = __shfl_xor(ti, 2);
        sr = fmaf(sg2, tr, orr);
        si = fmaf(sg2, ti, oii);
        tr = sr * w2r - si * w2i;
        ti = sr * w2i + si * w2r;
        orr = __shfl_xor(tr, 1);
        oii = __shfl_xor(ti, 1);
        vr[r] = fmaf(sg3, tr, orr);
        vi[r] = fmaf(sg3, ti, oii);
    }
}

// ---------------------------------------------------------------------------
// Kernel 1: Hilbert via register FFT; writes unit phasors as f16 planes.
// launch_bounds(256,2): 256-VGPR budget — (256,3) caused catastrophic scratch
// spill (R4: VGPR 84, +500 MB scratch traffic). Do not tighten.
// ---------------------------------------------------------------------------
__global__ __launch_bounds__(256, 2) void fft_hilbert_kernel(
    const float* __restrict__ x, _Float16* __restrict__ zr,
    _Float16* __restrict__ zi)
{
    __shared__ float lds[8192];   // 32 KB
    const int sig = blockIdx.x;
    const int t = threadIdx.x;
    const int j = t & 7, row = t >> 3;
    const int br3j = ((j & 1) << 2) | (j & 2) | ((j & 4) >> 2);

    float vr[32], vi[32];
    const float* xp = x + (size_t)sig * T_LEN;
    #pragma unroll
    for (int n1 = 0; n1 < 32; ++n1) { vr[n1] = xp[(n1 << 8) + t]; vi[n1] = 0.f; }

    big_fft(vr, vi, lds, t, j, row);

    // conj + Hilbert filter
    #pragma unroll
    for (int r = 0; r < 32; ++r) {
        const int k = row + (br5(r) << 5) + (br3j << 10);
        const float h = (k == 0 || k == 4096) ? 1.f : (k < 4096 ? 2.f : 0.f);
        vr[r] = vr[r] * h;
        vi[r] = -vi[r] * h;
    }

    // redistribute to natural order, two passes
    __syncthreads();
    #pragma unroll
    for (int r = 0; r < 32; ++r) {
        int a = row + (br5(r) << 5) + (br3j << 10);
        lds[a ^ (((a >> 10) & 3) << 3)] = vr[r];
    }
    __syncthreads();
    #pragma unroll
    for (int n1 = 0; n1 < 32; ++n1) {
        int a = (n1 << 8) + t;
        vr[n1] = lds[a ^ (((a >> 10) & 3) << 3)];
    }
    __syncthreads();
    #pragma unroll
    for (int r = 0; r < 32; ++r) {
        int a = row + (br5(r) << 5) + (br3j << 10);
        lds[a ^ (((a >> 10) & 3) << 3)] = vi[r];
    }
    __syncthreads();
    #pragma unroll
    for (int n1 = 0; n1 < 32; ++n1) {
        int a = (n1 << 8) + t;
        vi[n1] = lds[a ^ (((a >> 10) & 3) << 3)];
    }

    big_fft(vr, vi, lds, t, j, row);

    // conj + normalize; store f16 planes (fixed t-permutation, PLV-invariant)
    _Float16* zrp = zr + (size_t)sig * T_LEN;
    _Float16* zip = zi + (size_t)sig * T_LEN;
    #pragma unroll
    for (int r = 0; r < 32; ++r) {
        float ar = vr[r], ai = -vi[r];
        float inv = rsqrtf(ar * ar + ai * ai);
        zrp[(r << 8) + t] = (_Float16)(ar * inv);
        zip[(r << 8) + t] = (_Float16)(ai * inv);
    }
}

// ---------------------------------------------------------------------------
// Kernel 2: Gram via f16 MFMA (unchanged from R3). G_re = Re*Re^T + Im*Im^T,
// G_im = Im*Re^T - Re*Im^T.
// ---------------------------------------------------------------------------
#define GS 72   // LDS row stride in f16 (64 + 8 pad)
__global__ __launch_bounds__(256) void gram_kernel(
    const _Float16* __restrict__ zr, const _Float16* __restrict__ zi,
    float* __restrict__ part)
{
    __shared__ _Float16 ReS[64 * GS];
    __shared__ _Float16 ImS[64 * GS];
    const int b = blockIdx.x, sl = blockIdx.y, tid = threadIdx.x;
    const int w = tid >> 6, lane = tid & 63;
    const int mrow = lane & 15, quad = lane >> 4;

    f32x4 acc_re[4], acc_i1[4], acc_i2[4];
    #pragma unroll
    for (int tn = 0; tn < 4; ++tn) {
        acc_re[tn] = (f32x4)0.f; acc_i1[tn] = (f32x4)0.f; acc_i2[tn] = (f32x4)0.f;
    }

    const int k0 = sl * (T_LEN / NS_G);
    for (int chunk = 0; chunk < (T_LEN / NS_G) / 64; ++chunk) {
        const size_t gbase = (size_t)b * 64 * T_LEN + k0 + chunk * 64;
        __syncthreads();
        for (int pass = 0; pass < 2; ++pass) {
            int rw = (tid >> 3) + pass * 32;
            int c8 = (tid & 7) * 8;
            *(uint4*)&ReS[rw * GS + c8] = *(const uint4*)&zr[gbase + (size_t)rw * T_LEN + c8];
            *(uint4*)&ImS[rw * GS + c8] = *(const uint4*)&zi[gbase + (size_t)rw * T_LEN + c8];
        }
        __syncthreads();
        #pragma unroll
        for (int ks = 0; ks < 2; ++ks) {
            const int koff = ks * 32 + quad * 8;
            f16x8 a_re = *(f16x8*)&ReS[(w * 16 + mrow) * GS + koff];
            f16x8 a_im = *(f16x8*)&ImS[(w * 16 + mrow) * GS + koff];
            #pragma unroll
            for (int tn = 0; tn < 4; ++tn) {
                f16x8 b_re = *(f16x8*)&ReS[(tn * 16 + mrow) * GS + koff];
                f16x8 b_im = *(f16x8*)&ImS[(tn * 16 + mrow) * GS + koff];
                acc_re[tn] = __builtin_amdgcn_mfma_f32_16x16x32_f16(a_re, b_re, acc_re[tn], 0, 0, 0);
                acc_re[tn] = __builtin_amdgcn_mfma_f32_16x16x32_f16(a_im, b_im, acc_re[tn], 0, 0, 0);
                acc_i1[tn] = __builtin_amdgcn_mfma_f32_16x16x32_f16(a_im, b_re, acc_i1[tn], 0, 0, 0);
                acc_i2[tn] = __builtin_amdgcn_mfma_f32_16x16x32_f16(a_re, b_im, acc_i2[tn], 0, 0, 0);
            }
        }
    }

    // C/D layout: col = lane&15, row = quad*4 + reg
    float2* pp = (float2*)part + (size_t)(b * NS_G + sl) * 4096;
    #pragma unroll
    for (int tn = 0; tn < 4; ++tn)
        #pragma unroll
        for (int reg = 0; reg < 4; ++reg) {
            int m = w * 16 + quad * 4 + reg;
            int n = tn * 16 + mrow;
            float2 v;
            v.x = acc_re[tn][reg];
            v.y = acc_i1[tn][reg] - acc_i2[tn][reg];
            pp[m * 64 + n] = v;
        }
}

// ---------------------------------------------------------------------------
// Kernel 3: PLV-reduce (merged from plv_kernel) + GCN + MHA.
// Phase 1 reduces Gram partials -> conn (out0 + LDS), then proceeds as R2.
// ---------------------------------------------------------------------------
__global__ __launch_bounds__(1024) void gnn_mha_kernel(
    const float* __restrict__ part, const float* __restrict__ emb,
    const float* __restrict__ w1,   const float* __restrict__ b1,
    const float* __restrict__ w2,   const float* __restrict__ b2,
    const float* __restrict__ ipw,  const float* __restrict__ ipb,
    const float* __restrict__ opw,  const float* __restrict__ opb,
    float* __restrict__ out0, float* __restrict__ out1,
    float* __restrict__ out2)
{
    __shared__ float S[16384];
    const int b = blockIdx.x, tid = threadIdx.x;
    const int lane = tid & 63, w = tid >> 6;
    const int i0 = w * 4;

    // phase 1: reduce partials -> PLV -> S[0..4095] + out0
    const float2* pf = (const float2*)part;
    for (int e = tid; e < 4096; e += 1024) {
        float gr = 0.f, gi = 0.f;
        #pragma unroll
        for (int s = 0; s < NS_G; ++s) {
            float2 v = pf[(size_t)(b * NS_G + s) * 4096 + e];
            gr += v.x; gi += v.y;
        }
        int i = e >> 6, jj = e & 63;
        float val = (i == jj) ? 0.f
                              : sqrtf(gr * gr + gi * gi) * (1.0f / 8192.0f);
        S[e] = val;
        out0[(size_t)b * 4096 + e] = val;
    }
    __syncthreads();

    {   // M = conn @ emb
        float acc[4] = {0.f, 0.f, 0.f, 0.f};
        #pragma unroll 8
        for (int k = 0; k < 64; ++k) {
            float ev = emb[k * 64 + lane];
            #pragma unroll
            for (int r = 0; r < 4; ++r)
                acc[r] = fmaf(S[(i0 + r) * 64 + k], ev, acc[r]);
        }
        #pragma unroll
        for (int r = 0; r < 4; ++r) S[4096 + (i0 + r) * 64 + lane] = acc[r];
    }
    __syncthreads();

    {   // h1 = relu(M @ w1 + b1)
        float a0[4] = {0.f, 0.f, 0.f, 0.f}, a1[4] = {0.f, 0.f, 0.f, 0.f};
        #pragma unroll 8
        for (int k = 0; k < 64; ++k) {
            float wa = w1[k * 128 + lane];
            float wb = w1[k * 128 + 64 + lane];
            #pragma unroll
            for (int r = 0; r < 4; ++r) {
                float m = S[4096 + (i0 + r) * 64 + k];
                a0[r] = fmaf(m, wa, a0[r]);
                a1[r] = fmaf(m, wb, a1[r]);
            }
        }
        float bb0 = b1[lane], bb1 = b1[64 + lane];
        #pragma unroll
        for (int r = 0; r < 4; ++r) {
            S[8192 + (i0 + r) * 128 + lane]      = fmaxf(a0[r] + bb0, 0.f);
            S[8192 + (i0 + r) * 128 + 64 + lane] = fmaxf(a1[r] + bb1, 0.f);
        }
    }
    __syncthreads();

    {   // P = h1 @ w2
        float acc[4] = {0.f, 0.f, 0.f, 0.f};
        #pragma unroll 8
        for (int c = 0; c < 128; ++c) {
            float wv = w2[c * 64 + lane];
            #pragma unroll
            for (int r = 0; r < 4; ++r)
                acc[r] = fmaf(S[8192 + (i0 + r) * 128 + c], wv, acc[r]);
        }
        __syncthreads();
        #pragma unroll
        for (int r = 0; r < 4; ++r) S[4096 + (i0 + r) * 64 + lane] = acc[r];
    }
    __syncthreads();

    {   // h2 = conn @ P + b2 (in-place over conn rows)
        float acc[4] = {0.f, 0.f, 0.f, 0.f};
        #pragma unroll 8
        for (int k = 0; k < 64; ++k) {
            float pv = S[4096 + k * 64 + lane];
            #pragma unroll
            for (int r = 0; r < 4; ++r)
                acc[r] = fmaf(S[(i0 + r) * 64 + k], pv, acc[r]);
        }
        float bb = b2[lane];
        #pragma unroll
        for (int r = 0; r < 4; ++r) {
            float v = acc[r] + bb;
            S[(i0 + r) * 64 + lane] = v;
            out2[(size_t)b * 4096 + (i0 + r) * 64 + lane] = v;
        }
    }
    __syncthreads();

    {   // qkv
        float aq[4] = {0.f, 0.f, 0.f, 0.f};
        float ak[4] = {0.f, 0.f, 0.f, 0.f};
        float av[4] = {0.f, 0.f, 0.f, 0.f};
        #pragma unroll 8
        for (int k = 0; k < 64; ++k) {
            float wq = ipw[lane * 64 + k];
            float wk = ipw[(64 + lane) * 64 + k];
            float wv = ipw[(128 + lane) * 64 + k];
            #pragma unroll
            for (int r = 0; r < 4; ++r) {
                float hv = S[(i0 + r) * 64 + k];
                aq[r] = fmaf(hv, wq, aq[r]);
                ak[r] = fmaf(hv, wk, ak[r]);
                av[r] = fmaf(hv, wv, av[r]);
            }
        }
        float bq = ipb[lane], bk = ipb[64 + lane], bv = ipb[128 + lane];
        __syncthreads();
        #pragma unroll
        for (int r = 0; r < 4; ++r) {
            S[4096  + (i0 + r) * 64 + lane] = aq[r] + bq;
            S[8192  + (i0 + r) * 64 + lane] = ak[r] + bk;
            S[12288 + (i0 + r) * 64 + lane] = av[r] + bv;
        }
    }
    __syncthreads();

    const int h = w >> 1;
    float kk[8];
    #pragma unroll
    for (int d = 0; d < 8; ++d) kk[d] = S[8192 + lane * 64 + h * 8 + d];
    __syncthreads();

    {   // scores + softmax + attn@V
        const float iscale = 0.35355339059327373f;
        const int mc = lane >> 3, dd = lane & 7;
        for (int rr = 0; rr < 32; ++rr) {
            const int n = (w & 1) * 32 + rr;
            float s = 0.f;
            #pragma unroll
            for (int d = 0; d < 8; ++d)
                s = fmaf(S[4096 + n * 64 + h * 8 + d], kk[d], s);
            s *= iscale;
            float mx = s;
            #pragma unroll
            for (int off = 1; off < 64; off <<= 1)
                mx = fmaxf(mx, __shfl_xor(mx, off));
            float ev = __expf(s - mx);
            float sum = ev;
            #pragma unroll
            for (int off = 1; off < 64; off <<= 1)
                sum += __shfl_xor(sum, off);
            S[8192 + w * 68 + lane] = ev / sum;
            float o = 0.f;
            #pragma unroll
            for (int jx = 0; jx < 8; ++jx)
                o = fmaf(S[8192 + w * 68 + mc * 8 + jx],
                         S[12288 + (mc * 8 + jx) * 64 + h * 8 + dd], o);
            o += __shfl_xor(o, 8);
            o += __shfl_xor(o, 16);
            o += __shfl_xor(o, 32);
            if (lane < 8) S[n * 64 + h * 8 + lane] = o;
        }
    }
    __syncthreads();

    for (int e = tid; e < 4096; e += 1024) {
        int r = e >> 6, c = e & 63;
        S[8192 + r * 65 + c] = opw[e];
    }
    __syncthreads();

    {   // out1 = oh @ opw^T + opb
        float acc[4] = {0.f, 0.f, 0.f, 0.f};
        #pragma unroll 8
        for (int c = 0; c < 64; ++c) {
            float wv = S[8192 + lane * 65 + c];
            #pragma unroll
            for (int r = 0; r < 4; ++r)
                acc[r] = fmaf(S[(i0 + r) * 64 + c], wv, acc[r]);
        }
        float ob = opb[lane];
        #pragma unroll
        for (int r = 0; r < 4; ++r)
            out1[(size_t)b * 4096 + (i0 + r) * 64 + lane] = acc[r] + ob;
    }
}

// ---------------------------------------------------------------------------
extern "C" void kernel_launch(void* const* d_in, const int* in_sizes, int n_in,
                              void* d_out, int out_size, void* d_ws, size_t ws_size,
                              hipStream_t stream)
{
    const float* x   = (const float*)d_in[0];
    const float* emb = (const float*)d_in[1];
    const float* w1  = (const float*)d_in[2];
    const float* b1  = (const float*)d_in[3];
    const float* w2  = (const float*)d_in[4];
    const float* b2  = (const float*)d_in[5];
    const float* ipw = (const float*)d_in[6];
    const float* ipb = (const float*)d_in[7];
    const float* opw = (const float*)d_in[8];
    const float* opb = (const float*)d_in[9];

    float* out  = (float*)d_out;
    float* out0 = out;
    float* out1 = out + 131072;
    float* out2 = out + 262144;

    _Float16* zr = (_Float16*)d_ws;                     // 32 MB
    _Float16* zi = zr + (size_t)2048 * T_LEN;           // 32 MB
    float* part  = (float*)(zi + (size_t)2048 * T_LEN); // 8 MB

    hipLaunchKernelGGL(fft_hilbert_kernel, dim3(32 * 64), dim3(256), 0, stream,
                       x, zr, zi);
    hipLaunchKernelGGL(gram_kernel, dim3(32, NS_G), dim3(256), 0, stream,
                       zr, zi, part);
    hipLaunchKernelGGL(gnn_mha_kernel, dim3(32), dim3(1024), 0, stream,
                       part, emb, w1, b1, w2, b2, ipw, ipb, opw, opb,
                       out0, out1, out2);
}

// Round 6
// 336.667 us; speedup vs baseline: 2.2163x; 1.1534x over previous
//
#include <hip/hip_runtime.h>
#include <math.h>

#define T_LEN 8192
#define NS_G 8   // gram K-slices

typedef float  f32x4 __attribute__((ext_vector_type(4)));
typedef _Float16 f16x8 __attribute__((ext_vector_type(8)));

__device__ __forceinline__ constexpr int br5(int r) {
    return ((r & 1) << 4) | ((r & 2) << 2) | (r & 4) | ((r & 8) >> 2) | ((r & 16) >> 4);
}

// in-register 32-point DIF FFT; output slot r holds bin br5(r)
__device__ __forceinline__ void fft32(float* vr, float* vi)
{
    constexpr float TR[16] = {
        1.0f, 0.9807852804f, 0.9238795325f, 0.8314696123f,
        0.7071067812f, 0.5555702330f, 0.3826834324f, 0.1950903220f,
        0.0f, -0.1950903220f, -0.3826834324f, -0.5555702330f,
        -0.7071067812f, -0.8314696123f, -0.9238795325f, -0.9807852804f };
    constexpr float TI[16] = {
        0.0f, -0.1950903220f, -0.3826834324f, -0.5555702330f,
        -0.7071067812f, -0.8314696123f, -0.9238795325f, -0.9807852804f,
        -1.0f, -0.9807852804f, -0.9238795325f, -0.8314696123f,
        -0.7071067812f, -0.5555702330f, -0.3826834324f, -0.1950903220f };
    #pragma unroll
    for (int s = 0; s < 5; ++s) {
        const int half = 16 >> s;
        #pragma unroll
        for (int g = 0; g < (1 << s); ++g) {
            #pragma unroll
            for (int jj = 0; jj < half; ++jj) {
                const int i1 = g * (half << 1) + jj;
                const int i2 = i1 + half;
                const int q = jj << s;
                float ar = vr[i1], ai = vi[i1];
                float br = vr[i2], bi = vi[i2];
                vr[i1] = ar + br; vi[i1] = ai + bi;
                float dr = ar - br, di = ai - bi;
                vr[i2] = dr * TR[q] - di * TI[q];
                vi[i2] = dr * TI[q] + di * TR[q];
            }
        }
    }
}

// apply twiddle w^k1 (k1=1..31) to slot br5(k1) via iterative rotation chain
__device__ __forceinline__ void twiddle_chain(float* vr, float* vi, float ang)
{
    float c1, s1;
    __sincosf(ang, &s1, &c1);
    float cw = 1.f, sw = 0.f;
    #pragma unroll
    for (int k1 = 1; k1 < 32; ++k1) {
        float t0 = cw * c1 - sw * s1;
        sw = cw * s1 + sw * c1;
        cw = t0;
        const int r = br5(k1);
        float xr = vr[r], xi = vi[r];
        vr[r] = xr * cw - xi * sw;
        vi[r] = xr * sw + xi * cw;
    }
}

__device__ __forceinline__ int swz1(int a) { return a ^ (((a >> 8) & 3) << 3); }

// 8192-pt forward FFT; 32 KB LDS (float), transposes in re/im passes.
// Output: slot r of thread t holds bin k = (t>>3) + 32*br5(r) + 1024*br3(t&7).
__device__ __forceinline__ void big_fft(float* vr, float* vi, float* lds,
                                        int t, int j, int row)
{
    fft32(vr, vi);
    twiddle_chain(vr, vi, -7.669903939428206e-4f * (float)t);   // -2pi/8192 * t

    __syncthreads();
    #pragma unroll
    for (int r = 0; r < 32; ++r) lds[swz1((br5(r) << 8) + t)] = vr[r];
    __syncthreads();
    #pragma unroll
    for (int m1 = 0; m1 < 32; ++m1)
        vr[m1] = lds[swz1((row << 8) + (m1 << 3) + j)];
    __syncthreads();
    #pragma unroll
    for (int r = 0; r < 32; ++r) lds[swz1((br5(r) << 8) + t)] = vi[r];
    __syncthreads();
    #pragma unroll
    for (int m1 = 0; m1 < 32; ++m1)
        vi[m1] = lds[swz1((row << 8) + (m1 << 3) + j)];

    fft32(vr, vi);
    twiddle_chain(vr, vi, -0.02454369260617026f * (float)j);    // -2pi/256 * j

    // cross-lane FFT_8 over j (DIF; output lane j holds bin br3(j))
    const float R2 = 0.7071067811865475f;
    const int jm = j & 3;
    float w1r = 1.f, w1i = 0.f;
    if (j >= 4) {
        w1r = (jm == 0) ? 1.f : (jm == 1) ? R2 : (jm == 2) ? 0.f : -R2;
        w1i = (jm == 0) ? 0.f : (jm == 1) ? -R2 : (jm == 2) ? -1.f : -R2;
    }
    const float sg1 = (j < 4) ? 1.f : -1.f;
    const float sg2 = (j & 2) ? -1.f : 1.f;
    const bool tw2 = (j & 2) && (j & 1);
    const float w2r = tw2 ? 0.f : 1.f;
    const float w2i = tw2 ? -1.f : 0.f;
    const float sg3 = (j & 1) ? -1.f : 1.f;
    #pragma unroll
    for (int r = 0; r < 32; ++r) {
        float orr = __shfl_xor(vr[r], 4);
        float oii = __shfl_xor(vi[r], 4);
        float sr = fmaf(sg1, vr[r], orr);
        float si = fmaf(sg1, vi[r], oii);
        float tr = sr * w1r - si * w1i;
        float ti = sr * w1i + si * w1r;
        orr = __shfl_xor(tr, 2);
        oii = __shfl_xor(ti, 2);
        sr = fmaf(sg2, tr, orr);
        si = fmaf(sg2, ti, oii);
        tr = sr * w2r - si * w2i;
        ti = sr * w2i + si * w2r;
        orr = __shfl_xor(tr, 1);
        oii = __shfl_xor(ti, 1);
        vr[r] = fmaf(sg3, tr, orr);
        vi[r] = fmaf(sg3, ti, oii);
    }
}

// ---------------------------------------------------------------------------
// Kernel 1: Hilbert via register FFT; writes unit phasors as f16 planes.
// __launch_bounds__(256) with NO second arg: the compiler budgets VGPRs as
// 256/w (not 512/w) when min-waves w is given — (256,2) capped at 128 VGPR
// and (256,3) at 84, spilling vr/vi to scratch (+260..500 MB HBM traffic,
// R4/R5 counters). Unbounded -> ~204 VGPR, no spill. Do not add a 2nd arg.
// ---------------------------------------------------------------------------
__global__ __launch_bounds__(256) void fft_hilbert_kernel(
    const float* __restrict__ x, _Float16* __restrict__ zr,
    _Float16* __restrict__ zi)
{
    __shared__ float lds[8192];   // 32 KB
    const int sig = blockIdx.x;
    const int t = threadIdx.x;
    const int j = t & 7, row = t >> 3;
    const int br3j = ((j & 1) << 2) | (j & 2) | ((j & 4) >> 2);

    float vr[32], vi[32];
    const float* xp = x + (size_t)sig * T_LEN;
    #pragma unroll
    for (int n1 = 0; n1 < 32; ++n1) { vr[n1] = xp[(n1 << 8) + t]; vi[n1] = 0.f; }

    big_fft(vr, vi, lds, t, j, row);

    // conj + Hilbert filter
    #pragma unroll
    for (int r = 0; r < 32; ++r) {
        const int k = row + (br5(r) << 5) + (br3j << 10);
        const float h = (k == 0 || k == 4096) ? 1.f : (k < 4096 ? 2.f : 0.f);
        vr[r] = vr[r] * h;
        vi[r] = -vi[r] * h;
    }

    // redistribute to natural order, two passes
    __syncthreads();
    #pragma unroll
    for (int r = 0; r < 32; ++r) {
        int a = row + (br5(r) << 5) + (br3j << 10);
        lds[a ^ (((a >> 10) & 3) << 3)] = vr[r];
    }
    __syncthreads();
    #pragma unroll
    for (int n1 = 0; n1 < 32; ++n1) {
        int a = (n1 << 8) + t;
        vr[n1] = lds[a ^ (((a >> 10) & 3) << 3)];
    }
    __syncthreads();
    #pragma unroll
    for (int r = 0; r < 32; ++r) {
        int a = row + (br5(r) << 5) + (br3j << 10);
        lds[a ^ (((a >> 10) & 3) << 3)] = vi[r];
    }
    __syncthreads();
    #pragma unroll
    for (int n1 = 0; n1 < 32; ++n1) {
        int a = (n1 << 8) + t;
        vi[n1] = lds[a ^ (((a >> 10) & 3) << 3)];
    }

    big_fft(vr, vi, lds, t, j, row);

    // conj + normalize; store f16 planes (fixed t-permutation, PLV-invariant)
    _Float16* zrp = zr + (size_t)sig * T_LEN;
    _Float16* zip = zi + (size_t)sig * T_LEN;
    #pragma unroll
    for (int r = 0; r < 32; ++r) {
        float ar = vr[r], ai = -vi[r];
        float inv = rsqrtf(ar * ar + ai * ai);
        zrp[(r << 8) + t] = (_Float16)(ar * inv);
        zip[(r << 8) + t] = (_Float16)(ai * inv);
    }
}

// ---------------------------------------------------------------------------
// Kernel 2: Gram via f16 MFMA, software-pipelined staging (prefetch next
// chunk into regs during MFMA). G_re = Re*Re^T + Im*Im^T,
// G_im = Im*Re^T - Re*Im^T.
// ---------------------------------------------------------------------------
#define GS 72   // LDS row stride in f16 (64 + 8 pad)
__global__ __launch_bounds__(256) void gram_kernel(
    const _Float16* __restrict__ zr, const _Float16* __restrict__ zi,
    float* __restrict__ part)
{
    __shared__ _Float16 ReS[64 * GS];
    __shared__ _Float16 ImS[64 * GS];
    const int b = blockIdx.x, sl = blockIdx.y, tid = threadIdx.x;
    const int w = tid >> 6, lane = tid & 63;
    const int mrow = lane & 15, quad = lane >> 4;

    f32x4 acc_re[4], acc_i1[4], acc_i2[4];
    #pragma unroll
    for (int tn = 0; tn < 4; ++tn) {
        acc_re[tn] = (f32x4)0.f; acc_i1[tn] = (f32x4)0.f; acc_i2[tn] = (f32x4)0.f;
    }

    const int k0 = sl * (T_LEN / NS_G);
    const int r0 = tid >> 3, r1 = r0 + 32;   // staging rows
    const int c8 = (tid & 7) * 8;            // staging col (x8 f16)
    const size_t gb = (size_t)b * 64 * T_LEN + k0;

    // prefetch chunk 0
    uint4 pr0 = *(const uint4*)&zr[gb + (size_t)r0 * T_LEN + c8];
    uint4 pi0 = *(const uint4*)&zi[gb + (size_t)r0 * T_LEN + c8];
    uint4 pr1 = *(const uint4*)&zr[gb + (size_t)r1 * T_LEN + c8];
    uint4 pi1 = *(const uint4*)&zi[gb + (size_t)r1 * T_LEN + c8];

    const int NCH = (T_LEN / NS_G) / 64;
    for (int chunk = 0; chunk < NCH; ++chunk) {
        __syncthreads();
        *(uint4*)&ReS[r0 * GS + c8] = pr0;
        *(uint4*)&ImS[r0 * GS + c8] = pi0;
        *(uint4*)&ReS[r1 * GS + c8] = pr1;
        *(uint4*)&ImS[r1 * GS + c8] = pi1;
        __syncthreads();
        if (chunk + 1 < NCH) {
            const size_t gn = gb + (chunk + 1) * 64;
            pr0 = *(const uint4*)&zr[gn + (size_t)r0 * T_LEN + c8];
            pi0 = *(const uint4*)&zi[gn + (size_t)r0 * T_LEN + c8];
            pr1 = *(const uint4*)&zr[gn + (size_t)r1 * T_LEN + c8];
            pi1 = *(const uint4*)&zi[gn + (size_t)r1 * T_LEN + c8];
        }
        #pragma unroll
        for (int ks = 0; ks < 2; ++ks) {
            const int koff = ks * 32 + quad * 8;
            f16x8 a_re = *(f16x8*)&ReS[(w * 16 + mrow) * GS + koff];
            f16x8 a_im = *(f16x8*)&ImS[(w * 16 + mrow) * GS + koff];
            #pragma unroll
            for (int tn = 0; tn < 4; ++tn) {
                f16x8 b_re = *(f16x8*)&ReS[(tn * 16 + mrow) * GS + koff];
                f16x8 b_im = *(f16x8*)&ImS[(tn * 16 + mrow) * GS + koff];
                acc_re[tn] = __builtin_amdgcn_mfma_f32_16x16x32_f16(a_re, b_re, acc_re[tn], 0, 0, 0);
                acc_re[tn] = __builtin_amdgcn_mfma_f32_16x16x32_f16(a_im, b_im, acc_re[tn], 0, 0, 0);
                acc_i1[tn] = __builtin_amdgcn_mfma_f32_16x16x32_f16(a_im, b_re, acc_i1[tn], 0, 0, 0);
                acc_i2[tn] = __builtin_amdgcn_mfma_f32_16x16x32_f16(a_re, b_im, acc_i2[tn], 0, 0, 0);
            }
        }
    }

    // C/D layout: col = lane&15, row = quad*4 + reg
    float2* pp = (float2*)part + (size_t)(b * NS_G + sl) * 4096;
    #pragma unroll
    for (int tn = 0; tn < 4; ++tn)
        #pragma unroll
        for (int reg = 0; reg < 4; ++reg) {
            int m = w * 16 + quad * 4 + reg;
            int n = tn * 16 + mrow;
            float2 v;
            v.x = acc_re[tn][reg];
            v.y = acc_i1[tn][reg] - acc_i2[tn][reg];
            pp[m * 64 + n] = v;
        }
}

// ---------------------------------------------------------------------------
// Kernel 3: PLV-reduce + GCN + MHA (unchanged from R5)
// ---------------------------------------------------------------------------
__global__ __launch_bounds__(1024) void gnn_mha_kernel(
    const float* __restrict__ part, const float* __restrict__ emb,
    const float* __restrict__ w1,   const float* __restrict__ b1,
    const float* __restrict__ w2,   const float* __restrict__ b2,
    const float* __restrict__ ipw,  const float* __restrict__ ipb,
    const float* __restrict__ opw,  const float* __restrict__ opb,
    float* __restrict__ out0, float* __restrict__ out1,
    float* __restrict__ out2)
{
    __shared__ float S[16384];
    const int b = blockIdx.x, tid = threadIdx.x;
    const int lane = tid & 63, w = tid >> 6;
    const int i0 = w * 4;

    const float2* pf = (const float2*)part;
    for (int e = tid; e < 4096; e += 1024) {
        float gr = 0.f, gi = 0.f;
        #pragma unroll
        for (int s = 0; s < NS_G; ++s) {
            float2 v = pf[(size_t)(b * NS_G + s) * 4096 + e];
            gr += v.x; gi += v.y;
        }
        int i = e >> 6, jj = e & 63;
        float val = (i == jj) ? 0.f
                              : sqrtf(gr * gr + gi * gi) * (1.0f / 8192.0f);
        S[e] = val;
        out0[(size_t)b * 4096 + e] = val;
    }
    __syncthreads();

    {   // M = conn @ emb
        float acc[4] = {0.f, 0.f, 0.f, 0.f};
        #pragma unroll 8
        for (int k = 0; k < 64; ++k) {
            float ev = emb[k * 64 + lane];
            #pragma unroll
            for (int r = 0; r < 4; ++r)
                acc[r] = fmaf(S[(i0 + r) * 64 + k], ev, acc[r]);
        }
        #pragma unroll
        for (int r = 0; r < 4; ++r) S[4096 + (i0 + r) * 64 + lane] = acc[r];
    }
    __syncthreads();

    {   // h1 = relu(M @ w1 + b1)
        float a0[4] = {0.f, 0.f, 0.f, 0.f}, a1[4] = {0.f, 0.f, 0.f, 0.f};
        #pragma unroll 8
        for (int k = 0; k < 64; ++k) {
            float wa = w1[k * 128 + lane];
            float wb = w1[k * 128 + 64 + lane];
            #pragma unroll
            for (int r = 0; r < 4; ++r) {
                float m = S[4096 + (i0 + r) * 64 + k];
                a0[r] = fmaf(m, wa, a0[r]);
                a1[r] = fmaf(m, wb, a1[r]);
            }
        }
        float bb0 = b1[lane], bb1 = b1[64 + lane];
        #pragma unroll
        for (int r = 0; r < 4; ++r) {
            S[8192 + (i0 + r) * 128 + lane]      = fmaxf(a0[r] + bb0, 0.f);
            S[8192 + (i0 + r) * 128 + 64 + lane] = fmaxf(a1[r] + bb1, 0.f);
        }
    }
    __syncthreads();

    {   // P = h1 @ w2
        float acc[4] = {0.f, 0.f, 0.f, 0.f};
        #pragma unroll 8
        for (int c = 0; c < 128; ++c) {
            float wv = w2[c * 64 + lane];
            #pragma unroll
            for (int r = 0; r < 4; ++r)
                acc[r] = fmaf(S[8192 + (i0 + r) * 128 + c], wv, acc[r]);
        }
        __syncthreads();
        #pragma unroll
        for (int r = 0; r < 4; ++r) S[4096 + (i0 + r) * 64 + lane] = acc[r];
    }
    __syncthreads();

    {   // h2 = conn @ P + b2 (in-place over conn rows)
        float acc[4] = {0.f, 0.f, 0.f, 0.f};
        #pragma unroll 8
        for (int k = 0; k < 64; ++k) {
            float pv = S[4096 + k * 64 + lane];
            #pragma unroll
            for (int r = 0; r < 4; ++r)
                acc[r] = fmaf(S[(i0 + r) * 64 + k], pv, acc[r]);
        }
        float bb = b2[lane];
        #pragma unroll
        for (int r = 0; r < 4; ++r) {
            float v = acc[r] + bb;
            S[(i0 + r) * 64 + lane] = v;
            out2[(size_t)b * 4096 + (i0 + r) * 64 + lane] = v;
        }
    }
    __syncthreads();

    {   // qkv
        float aq[4] = {0.f, 0.f, 0.f, 0.f};
        float ak[4] = {0.f, 0.f, 0.f, 0.f};
        float av[4] = {0.f, 0.f, 0.f, 0.f};
        #pragma unroll 8
        for (int k = 0; k < 64; ++k) {
            float wq = ipw[lane * 64 + k];
            float wk = ipw[(64 + lane) * 64 + k];
            float wv = ipw[(128 + lane) * 64 + k];
            #pragma unroll
            for (int r = 0; r < 4; ++r) {
                float hv = S[(i0 + r) * 64 + k];
                aq[r] = fmaf(hv, wq, aq[r]);
                ak[r] = fmaf(hv, wk, ak[r]);
                av[r] = fmaf(hv, wv, av[r]);
            }
        }
        float bq = ipb[lane], bk = ipb[64 + lane], bv = ipb[128 + lane];
        __syncthreads();
        #pragma unroll
        for (int r = 0; r < 4; ++r) {
            S[4096  + (i0 + r) * 64 + lane] = aq[r] + bq;
            S[8192  + (i0 + r) * 64 + lane] = ak[r] + bk;
            S[12288 + (i0 + r) * 64 + lane] = av[r] + bv;
        }
    }
    __syncthreads();

    const int h = w >> 1;
    float kk[8];
    #pragma unroll
    for (int d = 0; d < 8; ++d) kk[d] = S[8192 + lane * 64 + h * 8 + d];
    __syncthreads();

    {   // scores + softmax + attn@V
        const float iscale = 0.35355339059327373f;
        const int mc = lane >> 3, dd = lane & 7;
        for (int rr = 0; rr < 32; ++rr) {
            const int n = (w & 1) * 32 + rr;
            float s = 0.f;
            #pragma unroll
            for (int d = 0; d < 8; ++d)
                s = fmaf(S[4096 + n * 64 + h * 8 + d], kk[d], s);
            s *= iscale;
            float mx = s;
            #pragma unroll
            for (int off = 1; off < 64; off <<= 1)
                mx = fmaxf(mx, __shfl_xor(mx, off));
            float ev = __expf(s - mx);
            float sum = ev;
            #pragma unroll
            for (int off = 1; off < 64; off <<= 1)
                sum += __shfl_xor(sum, off);
            S[8192 + w * 68 + lane] = ev / sum;
            float o = 0.f;
            #pragma unroll
            for (int jx = 0; jx < 8; ++jx)
                o = fmaf(S[8192 + w * 68 + mc * 8 + jx],
                         S[12288 + (mc * 8 + jx) * 64 + h * 8 + dd], o);
            o += __shfl_xor(o, 8);
            o += __shfl_xor(o, 16);
            o += __shfl_xor(o, 32);
            if (lane < 8) S[n * 64 + h * 8 + lane] = o;
        }
    }
    __syncthreads();

    for (int e = tid; e < 4096; e += 1024) {
        int r = e >> 6, c = e & 63;
        S[8192 + r * 65 + c] = opw[e];
    }
    __syncthreads();

    {   // out1 = oh @ opw^T + opb
        float acc[4] = {0.f, 0.f, 0.f, 0.f};
        #pragma unroll 8
        for (int c = 0; c < 64; ++c) {
            float wv = S[8192 + lane * 65 + c];
            #pragma unroll
            for (int r = 0; r < 4; ++r)
                acc[r] = fmaf(S[(i0 + r) * 64 + c], wv, acc[r]);
        }
        float ob = opb[lane];
        #pragma unroll
        for (int r = 0; r < 4; ++r)
            out1[(size_t)b * 4096 + (i0 + r) * 64 + lane] = acc[r] + ob;
    }
}

// ---------------------------------------------------------------------------
extern "C" void kernel_launch(void* const* d_in, const int* in_sizes, int n_in,
                              void* d_out, int out_size, void* d_ws, size_t ws_size,
                              hipStream_t stream)
{
    const float* x   = (const float*)d_in[0];
    const float* emb = (const float*)d_in[1];
    const float* w1  = (const float*)d_in[2];
    const float* b1  = (const float*)d_in[3];
    const float* w2  = (const float*)d_in[4];
    const float* b2  = (const float*)d_in[5];
    const float* ipw = (const float*)d_in[6];
    const float* ipb = (const float*)d_in[7];
    const float* opw = (const float*)d_in[8];
    const float* opb = (const float*)d_in[9];

    float* out  = (float*)d_out;
    float* out0 = out;
    float* out1 = out + 131072;
    float* out2 = out + 262144;

    _Float16* zr = (_Float16*)d_ws;                     // 32 MB
    _Float16* zi = zr + (size_t)2048 * T_LEN;           // 32 MB
    float* part  = (float*)(zi + (size_t)2048 * T_LEN); // 8 MB

    hipLaunchKernelGGL(fft_hilbert_kernel, dim3(32 * 64), dim3(256), 0, stream,
                       x, zr, zi);
    hipLaunchKernelGGL(gram_kernel, dim3(32, NS_G), dim3(256), 0, stream,
                       zr, zi, part);
    hipLaunchKernelGGL(gnn_mha_kernel, dim3(32), dim3(1024), 0, stream,
                       part, emb, w1, b1, w2, b2, ipw, ipb, opw, opb,
                       out0, out1, out2);
}